// Round 10
// baseline (563.734 us; speedup 1.0000x reference)
//
#include <hip/hip_runtime.h>
#include <math.h>

#define BB 8
#define LL 2048
#define DM 256
#define NH 8
#define DH 32
#define DFF 1024
#define SS 40
#define UU 40
#define BL (BB*LL)   // 16384
#define NSL 8        // attnupd L-slices per (b,h)

typedef unsigned short ushort_t;
typedef unsigned char uchar_t;
typedef __attribute__((ext_vector_type(8))) short short8;
typedef __attribute__((ext_vector_type(4))) float f32x4;

__device__ inline ushort_t f2b(float f)
{
    unsigned int u = __float_as_uint(f);
    u += 0x7fff + ((u >> 16) & 1);      // round-to-nearest-even
    return (ushort_t)(u >> 16);
}

__device__ inline void gload16(const void* g, const void* l)
{
    __builtin_amdgcn_global_load_lds(
        (const __attribute__((address_space(1))) unsigned int*)g,
        (__attribute__((address_space(3))) unsigned int*)l, 16, 0, 0);
}

// ---------------------------------------------------------------------------
// bf16 MFMA GEMM, m97 structure. 128x128 tile, BK=32, 256 thr.
// OUT_MODE: 0 fp32 RM | 1 QKV scatter (fp32 q,k,v BHLD + bf16 kT[l][bh][d])
//           2 bf16 RM | 3 fp32 RM + bf16 RM into aux
// ---------------------------------------------------------------------------
template<int RELU, int OUT_MODE>
__global__ __launch_bounds__(256)
void gemm_mfma(const ushort_t* __restrict__ A, const ushort_t* __restrict__ Bt,
               const float* __restrict__ bias, void* __restrict__ Cout,
               void* __restrict__ aux, int M, int N, int K)
{
    __shared__ ushort_t Asl[128 * 32];
    __shared__ ushort_t Bsl[128 * 32];

    const int t    = threadIdx.x;
    const int lane = t & 63;
    const int wv   = t >> 6;
    const int row0 = blockIdx.x * 128;
    const int col0 = blockIdx.y * 128;
    const int wr   = (wv >> 1) * 64;
    const int wc   = (wv & 1) * 64;
    const int quad = lane >> 4;
    const int l16  = lane & 15;

    f32x4 acc[4][4];
    #pragma unroll
    for (int i = 0; i < 4; ++i)
        #pragma unroll
        for (int j = 0; j < 4; ++j)
            acc[i][j] = 0.f;

    for (int k0 = 0; k0 < K; k0 += 32) {
        __syncthreads();
        #pragma unroll
        for (int r = 0; r < 2; ++r) {
            int g = r * 256 + t;
            const ushort_t* ga = A  + (size_t)(row0 + (g >> 2)) * K + k0 + (g & 3) * 8;
            const ushort_t* gb = Bt + (size_t)(col0 + (g >> 2)) * K + k0 + (g & 3) * 8;
            int lbase = (r * 256 + wv * 64) * 16;
            gload16(ga, (const char*)Asl + lbase);
            gload16(gb, (const char*)Bsl + lbase);
        }
        __syncthreads();

        short8 af[4], bfr[4];
        #pragma unroll
        for (int mi = 0; mi < 4; ++mi)
            af[mi] = *(const short8*)&Asl[(wr + mi * 16 + l16) * 32 + quad * 8];
        #pragma unroll
        for (int ni = 0; ni < 4; ++ni)
            bfr[ni] = *(const short8*)&Bsl[(wc + ni * 16 + l16) * 32 + quad * 8];
        #pragma unroll
        for (int mi = 0; mi < 4; ++mi)
            #pragma unroll
            for (int ni = 0; ni < 4; ++ni)
                acc[mi][ni] = __builtin_amdgcn_mfma_f32_16x16x32_bf16(
                    af[mi], bfr[ni], acc[mi][ni], 0, 0, 0);
    }

    #pragma unroll
    for (int mi = 0; mi < 4; ++mi) {
        #pragma unroll
        for (int ni = 0; ni < 4; ++ni) {
            int col = col0 + wc + ni * 16 + l16;
            float bb = bias[col];
            #pragma unroll
            for (int r = 0; r < 4; ++r) {
                int row = row0 + wr + mi * 16 + quad * 4 + r;
                float v = acc[mi][ni][r] + bb;
                if (RELU) v = v > 0.f ? v : 0.f;
                if (OUT_MODE == 0) {
                    ((float*)Cout)[(size_t)row * N + col] = v;
                } else if (OUT_MODE == 1) {
                    int tensor = col >> 8;          // 0=q 1=k 2=v
                    int c2 = col & 255;
                    int b  = row >> 11, l = row & (LL - 1);
                    int hh = c2 >> 5,  dh = c2 & 31;
                    int bh = b * NH + hh;
                    size_t bi = (((size_t)bh * LL + l) << 5) + dh;
                    ((float*)Cout)[(size_t)tensor * (BB*NH*LL*DH) + bi] = v;
                    if (tensor == 1)   // kT[l][bh][d] bf16 for metric
                        ((ushort_t*)aux)[(((size_t)l << 6) + bh) * 32 + dh] = f2b(v);
                } else if (OUT_MODE == 2) {
                    ((ushort_t*)Cout)[(size_t)row * N + col] = f2b(v);
                } else {
                    ((float*)Cout)[(size_t)row * N + col] = v;
                    ((ushort_t*)aux)[(size_t)row * N + col] = f2b(v);
                }
            }
        }
    }
}

// ---------------------------------------------------------------------------
// Fused GEMM (Mx256, K param) + residual + LayerNorm (+ optional MLP head):
//   h = LN(h + A@Bt^T + bias) * g + beta ; writes h fp32 + hb bf16.
// 32x256 tile, grid M/32 = 512 blocks (2/CU), 4 waves (wave = 64 cols).
// ---------------------------------------------------------------------------
template<int HEAD>
__global__ __launch_bounds__(256)
void gemmln_k(const ushort_t* __restrict__ A, const ushort_t* __restrict__ Bt,
              const float* __restrict__ bias, float* __restrict__ h,
              ushort_t* __restrict__ hb, const float* __restrict__ g,
              const float* __restrict__ beta, int K,
              const float* __restrict__ w1, const float* __restrict__ b1,
              const float* __restrict__ w2, const float* __restrict__ b2,
              float* __restrict__ out)
{
    __shared__ ushort_t Asl[32 * 32];    // 2 KB
    __shared__ ushort_t Bsl[256 * 32];   // 16 KB
    __shared__ float rs[4][32], rs2[4][32];
    __shared__ float hrowS[256];

    const int t    = threadIdx.x;
    const int lane = t & 63;
    const int wv   = t >> 6;
    const int row0 = blockIdx.x * 32;
    const int wc   = wv * 64;
    const int quad = lane >> 4;
    const int l16  = lane & 15;

    f32x4 acc[2][4];
    #pragma unroll
    for (int i = 0; i < 2; ++i)
        #pragma unroll
        for (int j = 0; j < 4; ++j)
            acc[i][j] = 0.f;

    for (int k0 = 0; k0 < K; k0 += 32) {
        __syncthreads();
        if (wv < 2) {   // A tile: 32 rows x 32 k = 2 KB, waves 0-1
            const ushort_t* ga = A + (size_t)(row0 + (t >> 2)) * K + k0 + (t & 3) * 8;
            gload16(ga, (const char*)Asl + wv * 1024);
        }
        #pragma unroll
        for (int r = 0; r < 4; ++r) {   // B tile: 256 rows x 32 k = 16 KB
            int gg = r * 256 + t;
            const ushort_t* gb = Bt + (size_t)(gg >> 2) * K + k0 + (gg & 3) * 8;
            gload16(gb, (const char*)Bsl + (r * 256 + wv * 64) * 16);
        }
        __syncthreads();

        short8 af[2], bfr[4];
        #pragma unroll
        for (int mi = 0; mi < 2; ++mi)
            af[mi] = *(const short8*)&Asl[(mi * 16 + l16) * 32 + quad * 8];
        #pragma unroll
        for (int ni = 0; ni < 4; ++ni)
            bfr[ni] = *(const short8*)&Bsl[(wc + ni * 16 + l16) * 32 + quad * 8];
        #pragma unroll
        for (int mi = 0; mi < 2; ++mi)
            #pragma unroll
            for (int ni = 0; ni < 4; ++ni)
                acc[mi][ni] = __builtin_amdgcn_mfma_f32_16x16x32_bf16(
                    af[mi], bfr[ni], acc[mi][ni], 0, 0, 0);
    }

    float gcol[4], bcol[4];
    #pragma unroll
    for (int ni = 0; ni < 4; ++ni) {
        int col = wc + ni * 16 + l16;
        gcol[ni] = g[col];
        bcol[ni] = beta[col];
    }
    float ps[2][4], ps2[2][4];
    #pragma unroll
    for (int mi = 0; mi < 2; ++mi) {
        #pragma unroll
        for (int r = 0; r < 4; ++r) {
            int row = row0 + mi * 16 + quad * 4 + r;
            float s = 0.f, s2 = 0.f;
            #pragma unroll
            for (int ni = 0; ni < 4; ++ni) {
                int col = wc + ni * 16 + l16;
                float v = acc[mi][ni][r] + bias[col] + h[(size_t)row * DM + col];
                acc[mi][ni][r] = v;
                s += v;
                s2 += v * v;
            }
            ps[mi][r] = s;
            ps2[mi][r] = s2;
        }
    }
    #pragma unroll
    for (int off = 1; off < 16; off <<= 1) {
        #pragma unroll
        for (int mi = 0; mi < 2; ++mi)
            #pragma unroll
            for (int r = 0; r < 4; ++r) {
                ps[mi][r]  += __shfl_xor(ps[mi][r],  off, 16);
                ps2[mi][r] += __shfl_xor(ps2[mi][r], off, 16);
            }
    }
    if (l16 == 0) {
        #pragma unroll
        for (int mi = 0; mi < 2; ++mi)
            #pragma unroll
            for (int r = 0; r < 4; ++r) {
                int lrow = mi * 16 + quad * 4 + r;
                rs[wv][lrow]  = ps[mi][r];
                rs2[wv][lrow] = ps2[mi][r];
            }
    }
    __syncthreads();

    #pragma unroll
    for (int mi = 0; mi < 2; ++mi) {
        #pragma unroll
        for (int r = 0; r < 4; ++r) {
            int lrow = mi * 16 + quad * 4 + r;
            int row  = row0 + lrow;
            float tot  = rs[0][lrow] + rs[1][lrow] + rs[2][lrow] + rs[3][lrow];
            float tot2 = rs2[0][lrow] + rs2[1][lrow] + rs2[2][lrow] + rs2[3][lrow];
            float mean = tot * (1.f / (float)DM);
            float var  = tot2 * (1.f / (float)DM) - mean * mean;
            float inv  = 1.0f / sqrtf(var + 1e-5f);
            #pragma unroll
            for (int ni = 0; ni < 4; ++ni) {
                int col = wc + ni * 16 + l16;
                float val = (acc[mi][ni][r] - mean) * inv * gcol[ni] + bcol[ni];
                h[(size_t)row * DM + col]  = val;
                hb[(size_t)row * DM + col] = f2b(val);
                if (HEAD && lrow == 31) hrowS[col] = val;   // last row of block
            }
        }
    }

    if (HEAD) {
        __syncthreads();
        // blocks covering row (b*2048 + 2047): blockIdx = b*64 + 63
        if ((blockIdx.x & 63) == 63 && t < 64) {
            int b = blockIdx.x >> 6;
            float s = 0.f;
            for (int kk = 0; kk < DM; ++kk)
                s = fmaf(hrowS[kk], w1[kk * 64 + t], s);
            s += b1[t];
            s = s > 0.f ? s : 0.f;
            float contrib = s * w2[t];
            #pragma unroll
            for (int off = 32; off > 0; off >>= 1)
                contrib += __shfl_down(contrib, off, 64);
            if (t == 0) out[b] = contrib + b2[0];
        }
    }
}

// ---------------------------------------------------------------------------
// fused preproc: all weight transposes+cvt, bias pack, x cvt in ONE dispatch.
// ---------------------------------------------------------------------------
__device__ inline void tcvt_dev(float (*tile)[33], const float* __restrict__ src,
                                ushort_t* __restrict__ dst, int K, int N,
                                int matStride, int bi)
{
    int tilesN = N >> 5;
    int tpm = (K >> 5) * tilesN;
    int m   = bi / tpm;
    int tid = bi % tpm;
    int k0 = (tid / tilesN) << 5, n0 = (tid % tilesN) << 5;
    const float* s = src + (size_t)m * K * N;
    ushort_t*    d = dst + (size_t)m * matStride;
    int r = threadIdx.x >> 5, c = threadIdx.x & 31;
    #pragma unroll
    for (int i = 0; i < 4; ++i)
        tile[r + 8 * i][c] = s[(size_t)(k0 + r + 8 * i) * N + n0 + c];
    __syncthreads();
    #pragma unroll
    for (int i = 0; i < 4; ++i)
        d[(size_t)(n0 + r + 8 * i) * K + k0 + c] = f2b(tile[c][r + 8 * i]);
}

__global__ __launch_bounds__(256)
void preproc_k(const float* __restrict__ wq, const float* __restrict__ wk,
               const float* __restrict__ wv, const float* __restrict__ wo,
               const float* __restrict__ wf1, const float* __restrict__ wf2,
               const float* __restrict__ w_in,
               const float* __restrict__ bq, const float* __restrict__ bk,
               const float* __restrict__ bv, const float* __restrict__ x,
               ushort_t* __restrict__ wqkvT, ushort_t* __restrict__ woT,
               ushort_t* __restrict__ wf1T, ushort_t* __restrict__ wf2T,
               ushort_t* __restrict__ w_inT, float* __restrict__ bqkv,
               ushort_t* __restrict__ xb16)
{
    __shared__ float tile[32][33];
    int b = blockIdx.x;
    if (b < 512) {
        int which = b >> 7, lb = b & 127;
        const float* src = which == 0 ? wq : which == 1 ? wk : which == 2 ? wv : wo;
        ushort_t* dst = which == 0 ? wqkvT : which == 1 ? wqkvT + 65536
                       : which == 2 ? wqkvT + 131072 : woT;
        int stride = which == 3 ? 65536 : 768 * 256;
        tcvt_dev(tile, src, dst, DM, DM, stride, lb);
    } else if (b < 1024) {
        tcvt_dev(tile, wf1, wf1T, DM, DFF, 1024 * 256, b - 512);
    } else if (b < 1536) {
        tcvt_dev(tile, wf2, wf2T, DFF, DM, 256 * 1024, b - 1024);
    } else if (b < 1544) {
        tcvt_dev(tile, w_in, w_inT, 32, DM, 256 * 32, b - 1536);
    } else if (b < 1550) {
        int t = (b - 1544) * 256 + threadIdx.x;
        int i = t / 768, j = t % 768;
        const float* s = j < 256 ? bq : (j < 512 ? bk : bv);
        bqkv[t] = s[i * 256 + (j & 255)];
    } else {
        int tid = (b - 1550) * 256 + threadIdx.x;
        float4 v = ((const float4*)x)[tid];
        unsigned int lo = f2b(v.x) | ((unsigned int)f2b(v.y) << 16);
        unsigned int hi = f2b(v.z) | ((unsigned int)f2b(v.w) << 16);
        ((uint2*)xb16)[tid] = make_uint2(lo, hi);
    }
}

// ---------------------------------------------------------------------------
// metric v3: lane = bh, wave = one query position l. kT[l][bh][d] reads are
// fully coalesced. Also zeroes jidx for its 4 l positions. grid 512 x 256.
// ---------------------------------------------------------------------------
__global__ __launch_bounds__(256)
void metric2_k(const float* __restrict__ qb, const ushort_t* __restrict__ kT,
               const int* __restrict__ idx, float* __restrict__ Mout,
               unsigned int* __restrict__ jidx32)
{
    __shared__ float mst[64][5];
    int t = threadIdx.x;
    int w = t >> 6, lane = t & 63;
    int l = blockIdx.x * 4 + w;

    // zero jidx for (b, l in this block's range): 8b x 4l x 8h bytes = 64 uints
    if (t < 64) {
        int zb = t >> 3, sel = t & 7;
        int zl = blockIdx.x * 4 + (sel >> 1), half = sel & 1;
        jidx32[(size_t)(zb * LL + zl) * 2 + half] = 0;
    }

    const float4* qr = (const float4*)(qb + ((size_t)(lane * LL + l) << 5));
    float4 q[8];
    #pragma unroll
    for (int i = 0; i < 8; ++i) q[i] = qr[i];

    int r40 = idx[l * SS + (lane < SS ? lane : SS - 1)];

    float mx = -3e38f, sm = 0.f;
    for (int s = 0; s < SS; ++s) {
        int r = __shfl(r40, s, 64);
        const uint4* kr = (const uint4*)(kT + (((size_t)r << 6) + lane) * 32);
        float d = 0.f;
        #pragma unroll
        for (int ww = 0; ww < 4; ++ww) {
            uint4 kv = kr[ww];
            float4 qa = q[2 * ww], qb2 = q[2 * ww + 1];
            d = fmaf(__uint_as_float(kv.x << 16),         qa.x, d);
            d = fmaf(__uint_as_float(kv.x & 0xffff0000u), qa.y, d);
            d = fmaf(__uint_as_float(kv.y << 16),         qa.z, d);
            d = fmaf(__uint_as_float(kv.y & 0xffff0000u), qa.w, d);
            d = fmaf(__uint_as_float(kv.z << 16),         qb2.x, d);
            d = fmaf(__uint_as_float(kv.z & 0xffff0000u), qb2.y, d);
            d = fmaf(__uint_as_float(kv.w << 16),         qb2.z, d);
            d = fmaf(__uint_as_float(kv.w & 0xffff0000u), qb2.w, d);
        }
        mx = fmaxf(mx, d);
        sm += d;
    }
    mst[lane][w] = mx - sm * (1.0f / (float)LL);
    __syncthreads();

    int bh = t >> 2, ls = t & 3;
    Mout[(size_t)bh * LL + blockIdx.x * 4 + ls] = mst[bh][ls];
}

// ---------------------------------------------------------------------------
// selectvm: fused topk (stage1 per-wave slices + stage2 rank-select) + vmean.
// grid 64 (one block per bh). Writes top, jidx (rank+1 bytes), vme.
// ---------------------------------------------------------------------------
__global__ __launch_bounds__(256)
void selectvm_k(const float* __restrict__ Mout, const float* __restrict__ vb,
                int* __restrict__ top, uchar_t* __restrict__ jidx,
                float* __restrict__ vme)
{
    __shared__ float cvS[320];
    __shared__ int   ciS[320];
    __shared__ float red[8][32];

    int bh = blockIdx.x;
    int t  = threadIdx.x;
    int lane = t & 63, w = t >> 6;

    // stage 1: each wave handles slices 2w and 2w+1 (verbatim topk1 inner)
    for (int ss = 0; ss < 2; ++ss) {
        int sl = w * 2 + ss;
        int l0 = sl << 8;
        float v[4];
        #pragma unroll
        for (int i = 0; i < 4; ++i)
            v[i] = Mout[(size_t)bh * LL + l0 + i * 64 + lane];

        for (int r = 0; r < UU; ++r) {
            float bv = -3e38f; int bi = 1 << 30;
            #pragma unroll
            for (int i = 0; i < 4; ++i) {
                int idx = l0 + i * 64 + lane;
                if (v[i] > bv || (v[i] == bv && idx < bi)) { bv = v[i]; bi = idx; }
            }
            #pragma unroll
            for (int off = 32; off > 0; off >>= 1) {
                float ov = __shfl_down(bv, off, 64);
                int   oi = __shfl_down(bi, off, 64);
                if (ov > bv || (ov == bv && oi < bi)) { bv = ov; bi = oi; }
            }
            bv = __shfl(bv, 0, 64);
            bi = __shfl(bi, 0, 64);
            if (lane == 0) { cvS[sl * UU + r] = bv; ciS[sl * UU + r] = bi; }
            int rel = bi - l0;
            if ((rel & 63) == lane) v[rel >> 6] = -3e38f;
        }
    }
    __syncthreads();

    // stage 2: rank-select (verbatim topk2)
    for (int c = t; c < 320; c += 256) {
        float mv = cvS[c]; int mi = ciS[c];
        int rank = 0;
        for (int j = 0; j < 320; ++j)
            rank += (cvS[j] > mv) || (cvS[j] == mv && ciS[j] < mi);
        if (rank < UU) {
            top[bh * UU + rank] = mi;
            int b = bh >> 3, hh = bh & 7;
            jidx[(size_t)(b * LL + mi) * 8 + hh] = (uchar_t)(rank + 1);
        }
    }

    // vmean for this bh
    int d = t & 31, part = t >> 5;
    const float* base = vb + ((size_t)bh * LL << 5);
    float s = 0.f;
    int l0 = part * 256;
    for (int i = 0; i < 256; ++i) s += base[((size_t)(l0 + i) << 5) + d];
    red[part][d] = s;
    __syncthreads();
    if (t < 32) {
        float tot = 0.f;
        #pragma unroll
        for (int p = 0; p < 8; ++p) tot += red[p][t];
        vme[bh * 32 + t] = tot * (1.f / (float)LL);
    }
}

// ---------------------------------------------------------------------------
// attnupd: block = bh*NSL + slice (512 blocks), 256 l per slice.
// ---------------------------------------------------------------------------
__global__ __launch_bounds__(256)
void attnupd_k(const float* __restrict__ qb, const float* __restrict__ kb,
               const float* __restrict__ vb, const int* __restrict__ top,
               float* __restrict__ mP, float* __restrict__ sP,
               float* __restrict__ OP)
{
    __shared__ float qs[UU * 32];        // 5 KB
    __shared__ float sc[UU * 256];       // 40 KB
    __shared__ float msh[UU];

    int blk = blockIdx.x;
    int sl  = blk & (NSL - 1);
    int bh  = blk >> 3;
    int t   = threadIdx.x;
    int l0  = sl << 8;

    for (int i = t; i < UU * 32; i += 256) {
        int j = i >> 5, dd = i & 31;
        qs[i] = qb[((size_t)(bh * LL + top[bh * UU + j]) << 5) + dd];
    }

    const float4* kr = (const float4*)(kb + ((size_t)(bh * LL + l0 + t) << 5));
    float4 k4[8];
    #pragma unroll
    for (int i = 0; i < 8; ++i) k4[i] = kr[i];
    __syncthreads();

    const float scale = 0.17677669529663687f;   // 1/sqrt(32)
    #pragma unroll 4
    for (int j = 0; j < UU; ++j) {
        float ds = 0.f;
        #pragma unroll
        for (int i = 0; i < 8; ++i) {
            float4 qv = *(const float4*)&qs[j * 32 + 4 * i];   // broadcast
            ds = fmaf(qv.x, k4[i].x, ds);
            ds = fmaf(qv.y, k4[i].y, ds);
            ds = fmaf(qv.z, k4[i].z, ds);
            ds = fmaf(qv.w, k4[i].w, ds);
        }
        sc[j * 256 + t] = ds * scale;
    }
    __syncthreads();

    int j8 = t >> 5, d = t & 31;
    #pragma unroll
    for (int g = 0; g < 5; ++g) {
        int j = g * 8 + j8;
        float4 a = *(const float4*)&sc[j * 256 + 4 * d];
        float4 b = *(const float4*)&sc[j * 256 + 128 + 4 * d];
        float m = fmaxf(fmaxf(fmaxf(a.x, a.y), fmaxf(a.z, a.w)),
                        fmaxf(fmaxf(b.x, b.y), fmaxf(b.z, b.w)));
        #pragma unroll
        for (int off = 16; off > 0; off >>= 1)
            m = fmaxf(m, __shfl_down(m, off, 64));
        if (d == 0) msh[j] = m;
    }
    __syncthreads();

    #pragma unroll 8
    for (int i = t; i < UU * 256; i += 256) {
        int j = i >> 8;
        sc[i] = __expf(sc[i] - msh[j]);
    }
    __syncthreads();

    int pq = bh * NSL + sl;

    #pragma unroll
    for (int g = 0; g < 5; ++g) {
        int j = g * 8 + j8;
        float4 a = *(const float4*)&sc[j * 256 + 4 * d];
        float4 b = *(const float4*)&sc[j * 256 + 128 + 4 * d];
        float s = a.x + a.y + a.z + a.w + b.x + b.y + b.z + b.w;
        #pragma unroll
        for (int off = 16; off > 0; off >>= 1)
            s += __shfl_down(s, off, 64);
        if (d == 0) { sP[pq * UU + j] = s; mP[pq * UU + j] = msh[j]; }
    }

    const float* vbase = vb + ((size_t)(bh * LL + l0) << 5) + d;
    float acc[5] = {0.f, 0.f, 0.f, 0.f, 0.f};
    #pragma unroll 4
    for (int i = 0; i < 64; ++i) {
        float v0 = vbase[(4 * i + 0) << 5];
        float v1 = vbase[(4 * i + 1) << 5];
        float v2 = vbase[(4 * i + 2) << 5];
        float v3 = vbase[(4 * i + 3) << 5];
        #pragma unroll
        for (int g = 0; g < 5; ++g) {
            float4 e4 = *(const float4*)&sc[(g * 8 + j8) * 256 + 4 * i];
            acc[g] = fmaf(e4.x, v0, acc[g]);
            acc[g] = fmaf(e4.y, v1, acc[g]);
            acc[g] = fmaf(e4.z, v2, acc[g]);
            acc[g] = fmaf(e4.w, v3, acc[g]);
        }
    }
    #pragma unroll
    for (int g = 0; g < 5; ++g)
        OP[((size_t)pq * UU + g * 8 + j8) * 32 + d] = acc[g];
}

// ---------------------------------------------------------------------------
// fillcomb: ctx bf16 = vmean broadcast; scattered (top) rows get the merged
// softmax update (combine logic inline via jidx rank byte). grid 8192 x 256.
// ---------------------------------------------------------------------------
__global__ __launch_bounds__(256)
void fillcomb_k(const float* __restrict__ vme, const uchar_t* __restrict__ jidx,
                const float* __restrict__ mP, const float* __restrict__ sP,
                const float* __restrict__ OP, ushort_t* __restrict__ ctxb)
{
    int tid = blockIdx.x * 256 + threadIdx.x;   // over BL*DM/2 pairs
    int pr   = tid & 127;
    int rowi = tid >> 7;          // b*2048 + l
    int b    = rowi >> 11;
    int hh   = pr >> 4;
    int j    = (int)jidx[(size_t)rowi * 8 + hh];

    float v0, v1;
    if (j == 0) {
        v0 = vme[(b << 8) + pr * 2];
        v1 = vme[(b << 8) + pr * 2 + 1];
    } else {
        int jj = j - 1;
        int bh = b * 8 + hh;
        int d0 = (pr * 2) & 31;
        float M = -3e38f;
        #pragma unroll
        for (int q = 0; q < NSL; ++q) M = fmaxf(M, mP[(bh * NSL + q) * UU + jj]);
        float S = 0.f, O0 = 0.f, O1 = 0.f;
        #pragma unroll
        for (int q = 0; q < NSL; ++q) {
            float wgt = __expf(mP[(bh * NSL + q) * UU + jj] - M);
            S  = fmaf(sP[(bh * NSL + q) * UU + jj], wgt, S);
            O0 = fmaf(OP[((size_t)(bh * NSL + q) * UU + jj) * 32 + d0], wgt, O0);
            O1 = fmaf(OP[((size_t)(bh * NSL + q) * UU + jj) * 32 + d0 + 1], wgt, O1);
        }
        v0 = O0 / S;
        v1 = O1 / S;
    }
    ((unsigned int*)ctxb)[tid] = (unsigned int)f2b(v0) | ((unsigned int)f2b(v1) << 16);
}

extern "C" void kernel_launch(void* const* d_in, const int* in_sizes, int n_in,
                              void* d_out, int out_size, void* d_ws, size_t ws_size,
                              hipStream_t stream)
{
    const float* x    = (const float*)d_in[0];
    const int*   idx  = (const int*)  d_in[1];
    const float* w_in = (const float*)d_in[2];
    const float* b_in = (const float*)d_in[3];
    const float* wq   = (const float*)d_in[4];
    const float* bq   = (const float*)d_in[5];
    const float* wk   = (const float*)d_in[6];
    const float* bk   = (const float*)d_in[7];
    const float* wv   = (const float*)d_in[8];
    const float* bv   = (const float*)d_in[9];
    const float* wo   = (const float*)d_in[10];
    const float* bo   = (const float*)d_in[11];
    const float* wf1  = (const float*)d_in[12];
    const float* bf1  = (const float*)d_in[13];
    const float* wf2  = (const float*)d_in[14];
    const float* bf2  = (const float*)d_in[15];
    const float* g1   = (const float*)d_in[16];
    const float* be1  = (const float*)d_in[17];
    const float* g2   = (const float*)d_in[18];
    const float* be2  = (const float*)d_in[19];
    const float* wfc1 = (const float*)d_in[20];
    const float* bfc1 = (const float*)d_in[21];
    const float* wfc2 = (const float*)d_in[22];
    const float* bfc2 = (const float*)d_in[23];
    float* out = (float*)d_out;

    float* ws = (float*)d_ws;
    float*    h     = ws;                          // [0, 4194304)
    float*    qkv   = ws + 4194304;                // [4194304, 16777216)
    float*    qb    = qkv;
    float*    kb    = qkv + 4194304;
    float*    vb    = qkv + 8388608;
    // attn scratch region (4194304 floats), all dead outside attention phase
    float*    attnS = ws + 16777216;
    ushort_t* kT16  = (ushort_t*)attnS;            //   fl [0, 2097152): kT bf16
    float*    Mbuf  = attnS + 2097152;             //   fl [2097152, 2228224)
    float*    OP    = attnS + 2285568;             //   655360
    float*    mP    = attnS + 2940928;             //   20480
    float*    sP    = attnS + 2961408;             //   20480
    uchar_t*  jidx  = (uchar_t*)(attnS + 2981888); //   32768 fl (131072 bytes)
    // long-lived scratch — offsets in FLOATS
    float*    scr   = ws + 20971520;
    ushort_t* xb16  = (ushort_t*)scr;              //   fl [0, 262144)
    float*    vme   = scr + 262144;                //   fl [262144, 264192)
    int*      top   = (int*)(scr + 264192);        //   fl [264192, 266752)
    ushort_t* hb    = (ushort_t*)(scr + 266752);   //   fl [266752, 2363904)
    ushort_t* wqkvT = (ushort_t*)(scr + 2363904);  //   fl [2363904, 2560512)
    ushort_t* woT   = (ushort_t*)(scr + 2560512);  //   fl [2560512, 2626048)
    ushort_t* wf1T  = (ushort_t*)(scr + 2626048);  //   fl [2626048, 2888192)
    ushort_t* wf2T  = (ushort_t*)(scr + 2888192);  //   fl [2888192, 3150336)
    ushort_t* w_inT = (ushort_t*)(scr + 3150336);  //   fl [3150336, 3154432)
    float*    bqkv  = scr + 3154432;               //   fl [3154432, 3155968)
    ushort_t* ctxb  = (ushort_t*)qkv;              // aliases dead q
    ushort_t* ffbb  = (ushort_t*)(qkv + 2097152);  // aliases dead q/k/v

    dim3 blk(256);

    preproc_k<<<dim3(2062), blk, 0, stream>>>(
        wq, wk, wv, wo, wf1, wf2, w_in, bq, bk, bv, x,
        wqkvT, woT, wf1T, wf2T, w_inT, bqkv, xb16);

    gemm_mfma<0,3><<<dim3(BL/128, 2), blk, 0, stream>>>(
        xb16, w_inT, b_in, (void*)h, (void*)hb, BL, DM, 32);

    for (int i = 0; i < 2; ++i) {
        gemm_mfma<0,1><<<dim3(BL/128, 6), blk, 0, stream>>>(
            hb, wqkvT + (size_t)i*768*256, bqkv + i*768, (void*)qkv, (void*)kT16,
            BL, 768, DM);

        metric2_k<<<dim3(512), blk, 0, stream>>>(
            qb, kT16, idx + (size_t)i*LL*SS, Mbuf, (unsigned int*)jidx);
        selectvm_k<<<dim3(BB*NH), blk, 0, stream>>>(Mbuf, vb, top, jidx, vme);
        attnupd_k<<<dim3(BB*NH*NSL), blk, 0, stream>>>(qb, kb, vb, top, mP, sP, OP);
        fillcomb_k<<<dim3(BL*DM/512), blk, 0, stream>>>(vme, jidx, mP, sP, OP, ctxb);

        // fused O-proj + residual + LN1
        gemmln_k<0><<<dim3(BL/32), blk, 0, stream>>>(
            ctxb, woT + (size_t)i*256*256, bo + i*DM, h, hb,
            g1 + i*DM, be1 + i*DM, DM,
            nullptr, nullptr, nullptr, nullptr, nullptr);

        gemm_mfma<1,2><<<dim3(BL/128, 8), blk, 0, stream>>>(
            hb, wf1T + (size_t)i*1024*256, bf1 + i*DFF, (void*)ffbb, nullptr, BL, DFF, DM);

        // fused FF2 + residual + LN2 (+ MLP head on the last layer)
        if (i == 1) {
            gemmln_k<1><<<dim3(BL/32), blk, 0, stream>>>(
                ffbb, wf2T + (size_t)i*256*1024, bf2 + i*DM, h, hb,
                g2 + i*DM, be2 + i*DM, DFF,
                wfc1, bfc1, wfc2, bfc2, out);
        } else {
            gemmln_k<0><<<dim3(BL/32), blk, 0, stream>>>(
                ffbb, wf2T + (size_t)i*256*1024, bf2 + i*DM, h, hb,
                g2 + i*DM, be2 + i*DM, DFF,
                nullptr, nullptr, nullptr, nullptr, nullptr);
        }
    }
}

// Round 11
// 513.937 us; speedup vs baseline: 1.0969x; 1.0969x over previous
//
#include <hip/hip_runtime.h>
#include <math.h>

#define BB 8
#define LL 2048
#define DM 256
#define NH 8
#define DH 32
#define DFF 1024
#define SS 40
#define UU 40
#define BL (BB*LL)   // 16384
#define NSL 8        // attnupd L-slices per (b,h)

typedef unsigned short ushort_t;
typedef unsigned char uchar_t;
typedef __attribute__((ext_vector_type(8))) short short8;
typedef __attribute__((ext_vector_type(4))) float f32x4;

__device__ inline ushort_t f2b(float f)
{
    unsigned int u = __float_as_uint(f);
    u += 0x7fff + ((u >> 16) & 1);      // round-to-nearest-even
    return (ushort_t)(u >> 16);
}

__device__ inline void gload16(const void* g, const void* l)
{
    __builtin_amdgcn_global_load_lds(
        (const __attribute__((address_space(1))) unsigned int*)g,
        (__attribute__((address_space(3))) unsigned int*)l, 16, 0, 0);
}

// ---------------------------------------------------------------------------
// bf16 MFMA GEMM, m97 structure. 128x128 tile, BK=32, 256 thr.
// OUT_MODE: 0 fp32 RM | 1 QKV scatter (fp32 q,k,v BHLD + bf16 kT[l][bh][d])
//           2 bf16 RM | 3 fp32 RM + bf16 RM into aux
// ---------------------------------------------------------------------------
template<int RELU, int OUT_MODE>
__global__ __launch_bounds__(256)
void gemm_mfma(const ushort_t* __restrict__ A, const ushort_t* __restrict__ Bt,
               const float* __restrict__ bias, void* __restrict__ Cout,
               void* __restrict__ aux, int M, int N, int K)
{
    __shared__ ushort_t Asl[128 * 32];
    __shared__ ushort_t Bsl[128 * 32];

    const int t    = threadIdx.x;
    const int lane = t & 63;
    const int wv   = t >> 6;
    const int row0 = blockIdx.x * 128;
    const int col0 = blockIdx.y * 128;
    const int wr   = (wv >> 1) * 64;
    const int wc   = (wv & 1) * 64;
    const int quad = lane >> 4;
    const int l16  = lane & 15;

    f32x4 acc[4][4];
    #pragma unroll
    for (int i = 0; i < 4; ++i)
        #pragma unroll
        for (int j = 0; j < 4; ++j)
            acc[i][j] = 0.f;

    for (int k0 = 0; k0 < K; k0 += 32) {
        __syncthreads();
        #pragma unroll
        for (int r = 0; r < 2; ++r) {
            int g = r * 256 + t;
            const ushort_t* ga = A  + (size_t)(row0 + (g >> 2)) * K + k0 + (g & 3) * 8;
            const ushort_t* gb = Bt + (size_t)(col0 + (g >> 2)) * K + k0 + (g & 3) * 8;
            int lbase = (r * 256 + wv * 64) * 16;
            gload16(ga, (const char*)Asl + lbase);
            gload16(gb, (const char*)Bsl + lbase);
        }
        __syncthreads();

        short8 af[4], bfr[4];
        #pragma unroll
        for (int mi = 0; mi < 4; ++mi)
            af[mi] = *(const short8*)&Asl[(wr + mi * 16 + l16) * 32 + quad * 8];
        #pragma unroll
        for (int ni = 0; ni < 4; ++ni)
            bfr[ni] = *(const short8*)&Bsl[(wc + ni * 16 + l16) * 32 + quad * 8];
        #pragma unroll
        for (int mi = 0; mi < 4; ++mi)
            #pragma unroll
            for (int ni = 0; ni < 4; ++ni)
                acc[mi][ni] = __builtin_amdgcn_mfma_f32_16x16x32_bf16(
                    af[mi], bfr[ni], acc[mi][ni], 0, 0, 0);
    }

    #pragma unroll
    for (int mi = 0; mi < 4; ++mi) {
        #pragma unroll
        for (int ni = 0; ni < 4; ++ni) {
            int col = col0 + wc + ni * 16 + l16;
            float bb = bias[col];
            #pragma unroll
            for (int r = 0; r < 4; ++r) {
                int row = row0 + wr + mi * 16 + quad * 4 + r;
                float v = acc[mi][ni][r] + bb;
                if (RELU) v = v > 0.f ? v : 0.f;
                if (OUT_MODE == 0) {
                    ((float*)Cout)[(size_t)row * N + col] = v;
                } else if (OUT_MODE == 1) {
                    int tensor = col >> 8;          // 0=q 1=k 2=v
                    int c2 = col & 255;
                    int b  = row >> 11, l = row & (LL - 1);
                    int hh = c2 >> 5,  dh = c2 & 31;
                    int bh = b * NH + hh;
                    size_t bi = (((size_t)bh * LL + l) << 5) + dh;
                    ((float*)Cout)[(size_t)tensor * (BB*NH*LL*DH) + bi] = v;
                    if (tensor == 1)   // kT[l][bh][d] bf16 for metric
                        ((ushort_t*)aux)[(((size_t)l << 6) + bh) * 32 + dh] = f2b(v);
                } else if (OUT_MODE == 2) {
                    ((ushort_t*)Cout)[(size_t)row * N + col] = f2b(v);
                } else {
                    ((float*)Cout)[(size_t)row * N + col] = v;
                    ((ushort_t*)aux)[(size_t)row * N + col] = f2b(v);
                }
            }
        }
    }
}

// ---------------------------------------------------------------------------
// Fused GEMM (Mx256, K param) + residual + LayerNorm (+ optional MLP head):
//   h = LN(h + A@Bt^T + bias) * g + beta ; writes h fp32 + hb bf16.
// 32x256 tile, grid M/32 = 512 blocks (2/CU), 4 waves (wave = 64 cols).
// ---------------------------------------------------------------------------
template<int HEAD>
__global__ __launch_bounds__(256)
void gemmln_k(const ushort_t* __restrict__ A, const ushort_t* __restrict__ Bt,
              const float* __restrict__ bias, float* __restrict__ h,
              ushort_t* __restrict__ hb, const float* __restrict__ g,
              const float* __restrict__ beta, int K,
              const float* __restrict__ w1, const float* __restrict__ b1,
              const float* __restrict__ w2, const float* __restrict__ b2,
              float* __restrict__ out)
{
    __shared__ ushort_t Asl[32 * 32];    // 2 KB
    __shared__ ushort_t Bsl[256 * 32];   // 16 KB
    __shared__ float rs[4][32], rs2[4][32];
    __shared__ float hrowS[256];

    const int t    = threadIdx.x;
    const int lane = t & 63;
    const int wv   = t >> 6;
    const int row0 = blockIdx.x * 32;
    const int wc   = wv * 64;
    const int quad = lane >> 4;
    const int l16  = lane & 15;

    f32x4 acc[2][4];
    #pragma unroll
    for (int i = 0; i < 2; ++i)
        #pragma unroll
        for (int j = 0; j < 4; ++j)
            acc[i][j] = 0.f;

    for (int k0 = 0; k0 < K; k0 += 32) {
        __syncthreads();
        if (wv < 2) {   // A tile: 32 rows x 32 k = 2 KB, waves 0-1
            const ushort_t* ga = A + (size_t)(row0 + (t >> 2)) * K + k0 + (t & 3) * 8;
            gload16(ga, (const char*)Asl + wv * 1024);
        }
        #pragma unroll
        for (int r = 0; r < 4; ++r) {   // B tile: 256 rows x 32 k = 16 KB
            int gg = r * 256 + t;
            const ushort_t* gb = Bt + (size_t)(gg >> 2) * K + k0 + (gg & 3) * 8;
            gload16(gb, (const char*)Bsl + (r * 256 + wv * 64) * 16);
        }
        __syncthreads();

        short8 af[2], bfr[4];
        #pragma unroll
        for (int mi = 0; mi < 2; ++mi)
            af[mi] = *(const short8*)&Asl[(mi * 16 + l16) * 32 + quad * 8];
        #pragma unroll
        for (int ni = 0; ni < 4; ++ni)
            bfr[ni] = *(const short8*)&Bsl[(wc + ni * 16 + l16) * 32 + quad * 8];
        #pragma unroll
        for (int mi = 0; mi < 2; ++mi)
            #pragma unroll
            for (int ni = 0; ni < 4; ++ni)
                acc[mi][ni] = __builtin_amdgcn_mfma_f32_16x16x32_bf16(
                    af[mi], bfr[ni], acc[mi][ni], 0, 0, 0);
    }

    float gcol[4], bcol[4];
    #pragma unroll
    for (int ni = 0; ni < 4; ++ni) {
        int col = wc + ni * 16 + l16;
        gcol[ni] = g[col];
        bcol[ni] = beta[col];
    }
    float ps[2][4], ps2[2][4];
    #pragma unroll
    for (int mi = 0; mi < 2; ++mi) {
        #pragma unroll
        for (int r = 0; r < 4; ++r) {
            int row = row0 + mi * 16 + quad * 4 + r;
            float s = 0.f, s2 = 0.f;
            #pragma unroll
            for (int ni = 0; ni < 4; ++ni) {
                int col = wc + ni * 16 + l16;
                float v = acc[mi][ni][r] + bias[col] + h[(size_t)row * DM + col];
                acc[mi][ni][r] = v;
                s += v;
                s2 += v * v;
            }
            ps[mi][r] = s;
            ps2[mi][r] = s2;
        }
    }
    #pragma unroll
    for (int off = 1; off < 16; off <<= 1) {
        #pragma unroll
        for (int mi = 0; mi < 2; ++mi)
            #pragma unroll
            for (int r = 0; r < 4; ++r) {
                ps[mi][r]  += __shfl_xor(ps[mi][r],  off, 16);
                ps2[mi][r] += __shfl_xor(ps2[mi][r], off, 16);
            }
    }
    if (l16 == 0) {
        #pragma unroll
        for (int mi = 0; mi < 2; ++mi)
            #pragma unroll
            for (int r = 0; r < 4; ++r) {
                int lrow = mi * 16 + quad * 4 + r;
                rs[wv][lrow]  = ps[mi][r];
                rs2[wv][lrow] = ps2[mi][r];
            }
    }
    __syncthreads();

    #pragma unroll
    for (int mi = 0; mi < 2; ++mi) {
        #pragma unroll
        for (int r = 0; r < 4; ++r) {
            int lrow = mi * 16 + quad * 4 + r;
            int row  = row0 + lrow;
            float tot  = rs[0][lrow] + rs[1][lrow] + rs[2][lrow] + rs[3][lrow];
            float tot2 = rs2[0][lrow] + rs2[1][lrow] + rs2[2][lrow] + rs2[3][lrow];
            float mean = tot * (1.f / (float)DM);
            float var  = tot2 * (1.f / (float)DM) - mean * mean;
            float inv  = 1.0f / sqrtf(var + 1e-5f);
            #pragma unroll
            for (int ni = 0; ni < 4; ++ni) {
                int col = wc + ni * 16 + l16;
                float val = (acc[mi][ni][r] - mean) * inv * gcol[ni] + bcol[ni];
                h[(size_t)row * DM + col]  = val;
                hb[(size_t)row * DM + col] = f2b(val);
                if (HEAD && lrow == 31) hrowS[col] = val;   // last row of block
            }
        }
    }

    if (HEAD) {
        __syncthreads();
        // blocks covering row (b*2048 + 2047): blockIdx = b*64 + 63
        if ((blockIdx.x & 63) == 63 && t < 64) {
            int b = blockIdx.x >> 6;
            float s = 0.f;
            for (int kk = 0; kk < DM; ++kk)
                s = fmaf(hrowS[kk], w1[kk * 64 + t], s);
            s += b1[t];
            s = s > 0.f ? s : 0.f;
            float contrib = s * w2[t];
            #pragma unroll
            for (int off = 32; off > 0; off >>= 1)
                contrib += __shfl_down(contrib, off, 64);
            if (t == 0) out[b] = contrib + b2[0];
        }
    }
}

// ---------------------------------------------------------------------------
// fused preproc: all weight transposes+cvt, bias pack, x cvt in ONE dispatch.
// ---------------------------------------------------------------------------
__device__ inline void tcvt_dev(float (*tile)[33], const float* __restrict__ src,
                                ushort_t* __restrict__ dst, int K, int N,
                                int matStride, int bi)
{
    int tilesN = N >> 5;
    int tpm = (K >> 5) * tilesN;
    int m   = bi / tpm;
    int tid = bi % tpm;
    int k0 = (tid / tilesN) << 5, n0 = (tid % tilesN) << 5;
    const float* s = src + (size_t)m * K * N;
    ushort_t*    d = dst + (size_t)m * matStride;
    int r = threadIdx.x >> 5, c = threadIdx.x & 31;
    #pragma unroll
    for (int i = 0; i < 4; ++i)
        tile[r + 8 * i][c] = s[(size_t)(k0 + r + 8 * i) * N + n0 + c];
    __syncthreads();
    #pragma unroll
    for (int i = 0; i < 4; ++i)
        d[(size_t)(n0 + r + 8 * i) * K + k0 + c] = f2b(tile[c][r + 8 * i]);
}

__global__ __launch_bounds__(256)
void preproc_k(const float* __restrict__ wq, const float* __restrict__ wk,
               const float* __restrict__ wv, const float* __restrict__ wo,
               const float* __restrict__ wf1, const float* __restrict__ wf2,
               const float* __restrict__ w_in,
               const float* __restrict__ bq, const float* __restrict__ bk,
               const float* __restrict__ bv, const float* __restrict__ x,
               ushort_t* __restrict__ wqkvT, ushort_t* __restrict__ woT,
               ushort_t* __restrict__ wf1T, ushort_t* __restrict__ wf2T,
               ushort_t* __restrict__ w_inT, float* __restrict__ bqkv,
               ushort_t* __restrict__ xb16)
{
    __shared__ float tile[32][33];
    int b = blockIdx.x;
    if (b < 512) {
        int which = b >> 7, lb = b & 127;
        const float* src = which == 0 ? wq : which == 1 ? wk : which == 2 ? wv : wo;
        ushort_t* dst = which == 0 ? wqkvT : which == 1 ? wqkvT + 65536
                       : which == 2 ? wqkvT + 131072 : woT;
        int stride = which == 3 ? 65536 : 768 * 256;
        tcvt_dev(tile, src, dst, DM, DM, stride, lb);
    } else if (b < 1024) {
        tcvt_dev(tile, wf1, wf1T, DM, DFF, 1024 * 256, b - 512);
    } else if (b < 1536) {
        tcvt_dev(tile, wf2, wf2T, DFF, DM, 256 * 1024, b - 1024);
    } else if (b < 1544) {
        tcvt_dev(tile, w_in, w_inT, 32, DM, 256 * 32, b - 1536);
    } else if (b < 1550) {
        int t = (b - 1544) * 256 + threadIdx.x;
        int i = t / 768, j = t % 768;
        const float* s = j < 256 ? bq : (j < 512 ? bk : bv);
        bqkv[t] = s[i * 256 + (j & 255)];
    } else {
        int tid = (b - 1550) * 256 + threadIdx.x;
        float4 v = ((const float4*)x)[tid];
        unsigned int lo = f2b(v.x) | ((unsigned int)f2b(v.y) << 16);
        unsigned int hi = f2b(v.z) | ((unsigned int)f2b(v.w) << 16);
        ((uint2*)xb16)[tid] = make_uint2(lo, hi);
    }
}

// ---------------------------------------------------------------------------
// metric v3: lane = bh, wave = one query position l. kT[l][bh][d] reads are
// fully coalesced. Also zeroes jidx for its 4 l positions. grid 512 x 256.
// ---------------------------------------------------------------------------
__global__ __launch_bounds__(256)
void metric2_k(const float* __restrict__ qb, const ushort_t* __restrict__ kT,
               const int* __restrict__ idx, float* __restrict__ Mout,
               unsigned int* __restrict__ jidx32)
{
    __shared__ float mst[64][5];
    int t = threadIdx.x;
    int w = t >> 6, lane = t & 63;
    int l = blockIdx.x * 4 + w;

    // zero jidx for (b, l in this block's range): 8b x 4l x 8h bytes = 64 uints
    if (t < 64) {
        int zb = t >> 3, sel = t & 7;
        int zl = blockIdx.x * 4 + (sel >> 1), half = sel & 1;
        jidx32[(size_t)(zb * LL + zl) * 2 + half] = 0;
    }

    const float4* qr = (const float4*)(qb + ((size_t)(lane * LL + l) << 5));
    float4 q[8];
    #pragma unroll
    for (int i = 0; i < 8; ++i) q[i] = qr[i];

    int r40 = idx[l * SS + (lane < SS ? lane : SS - 1)];

    float mx = -3e38f, sm = 0.f;
    for (int s = 0; s < SS; ++s) {
        int r = __shfl(r40, s, 64);
        const uint4* kr = (const uint4*)(kT + (((size_t)r << 6) + lane) * 32);
        float d = 0.f;
        #pragma unroll
        for (int ww = 0; ww < 4; ++ww) {
            uint4 kv = kr[ww];
            float4 qa = q[2 * ww], qb2 = q[2 * ww + 1];
            d = fmaf(__uint_as_float(kv.x << 16),         qa.x, d);
            d = fmaf(__uint_as_float(kv.x & 0xffff0000u), qa.y, d);
            d = fmaf(__uint_as_float(kv.y << 16),         qa.z, d);
            d = fmaf(__uint_as_float(kv.y & 0xffff0000u), qa.w, d);
            d = fmaf(__uint_as_float(kv.z << 16),         qb2.x, d);
            d = fmaf(__uint_as_float(kv.z & 0xffff0000u), qb2.y, d);
            d = fmaf(__uint_as_float(kv.w << 16),         qb2.z, d);
            d = fmaf(__uint_as_float(kv.w & 0xffff0000u), qb2.w, d);
        }
        mx = fmaxf(mx, d);
        sm += d;
    }
    mst[lane][w] = mx - sm * (1.0f / (float)LL);
    __syncthreads();

    int bh = t >> 2, ls = t & 3;
    Mout[(size_t)bh * LL + blockIdx.x * 4 + ls] = mst[bh][ls];
}

// ---------------------------------------------------------------------------
// topk stage 1: wave-synchronous per-slice top-40 (no barriers). grid 128.
// ---------------------------------------------------------------------------
__global__ __launch_bounds__(256)
void topk1_k(const float* __restrict__ Mout,
             float* __restrict__ cand_v, int* __restrict__ cand_i)
{
    int lane = threadIdx.x & 63;
    int slg  = blockIdx.x * 4 + (threadIdx.x >> 6);   // 0..511
    int bh   = slg >> 3;
    int l0   = (slg & 7) << 8;

    float v[4];
    #pragma unroll
    for (int i = 0; i < 4; ++i)
        v[i] = Mout[(size_t)bh * LL + l0 + i * 64 + lane];

    for (int r = 0; r < UU; ++r) {
        float bv = -3e38f; int bi = 1 << 30;
        #pragma unroll
        for (int i = 0; i < 4; ++i) {
            int idx = l0 + i * 64 + lane;
            if (v[i] > bv || (v[i] == bv && idx < bi)) { bv = v[i]; bi = idx; }
        }
        #pragma unroll
        for (int off = 32; off > 0; off >>= 1) {
            float ov = __shfl_down(bv, off, 64);
            int   oi = __shfl_down(bi, off, 64);
            if (ov > bv || (ov == bv && oi < bi)) { bv = ov; bi = oi; }
        }
        bv = __shfl(bv, 0, 64);
        bi = __shfl(bi, 0, 64);
        if (lane == 0) {
            cand_v[slg * UU + r] = bv;
            cand_i[slg * UU + r] = bi;
        }
        int rel = bi - l0;
        if ((rel & 63) == lane) v[rel >> 6] = -3e38f;
    }
}

// topk stage 2: rank-select top-40 from 320 candidates; writes top + jidx byte.
__global__ __launch_bounds__(256)
void topk2_k(const float* __restrict__ cand_v, const int* __restrict__ cand_i,
             int* __restrict__ top, uchar_t* __restrict__ jidx)
{
    __shared__ float cv[320];
    __shared__ int   ci[320];
    int bh = blockIdx.x, t = threadIdx.x;
    for (int i = t; i < 320; i += 256) {
        cv[i] = cand_v[bh * 320 + i];
        ci[i] = cand_i[bh * 320 + i];
    }
    __syncthreads();
    for (int c = t; c < 320; c += 256) {
        float mv = cv[c]; int mi = ci[c];
        int rank = 0;
        for (int j = 0; j < 320; ++j)
            rank += (cv[j] > mv) || (cv[j] == mv && ci[j] < mi);
        if (rank < UU) {
            top[bh * UU + rank] = mi;
            int b = bh >> 3, hh = bh & 7;
            jidx[(size_t)(b * LL + mi) * 8 + hh] = (uchar_t)(rank + 1);
        }
    }
}

// vmean partials: grid 512 (bh x 8 slices)
__global__ __launch_bounds__(256)
void vmeanp_k(const float* __restrict__ vb, float* __restrict__ vmeP)
{
    __shared__ float red[8][32];
    int blk = blockIdx.x;
    int bh = blk >> 3, sl = blk & 7;
    int t = threadIdx.x;
    int d = t & 31, part = t >> 5;
    const float* base = vb + ((size_t)(bh * LL + sl * 256 + part * 32) << 5);
    float s = 0.f;
    #pragma unroll 8
    for (int i = 0; i < 32; ++i) s += base[(i << 5) + d];
    red[part][d] = s;
    __syncthreads();
    if (t < 32) {
        float tot = 0.f;
        #pragma unroll
        for (int p = 0; p < 8; ++p) tot += red[p][t];
        vmeP[blk * 32 + t] = tot;
    }
}

__global__ __launch_bounds__(256)
void vfin_k(const float* __restrict__ vmeP, float* __restrict__ vme)
{
    int tid = blockIdx.x * 256 + threadIdx.x;   // < 2048
    int bh = tid >> 5, d = tid & 31;
    float s = 0.f;
    #pragma unroll
    for (int sl = 0; sl < 8; ++sl) s += vmeP[(bh * 8 + sl) * 32 + d];
    vme[tid] = s * (1.f / (float)LL);
}

// ---------------------------------------------------------------------------
// attnupd: block = bh*NSL + slice (512 blocks), 256 l per slice.
// ---------------------------------------------------------------------------
__global__ __launch_bounds__(256)
void attnupd_k(const float* __restrict__ qb, const float* __restrict__ kb,
               const float* __restrict__ vb, const int* __restrict__ top,
               float* __restrict__ mP, float* __restrict__ sP,
               float* __restrict__ OP)
{
    __shared__ float qs[UU * 32];        // 5 KB
    __shared__ float sc[UU * 256];       // 40 KB
    __shared__ float msh[UU];

    int blk = blockIdx.x;
    int sl  = blk & (NSL - 1);
    int bh  = blk >> 3;
    int t   = threadIdx.x;
    int l0  = sl << 8;

    for (int i = t; i < UU * 32; i += 256) {
        int j = i >> 5, dd = i & 31;
        qs[i] = qb[((size_t)(bh * LL + top[bh * UU + j]) << 5) + dd];
    }

    const float4* kr = (const float4*)(kb + ((size_t)(bh * LL + l0 + t) << 5));
    float4 k4[8];
    #pragma unroll
    for (int i = 0; i < 8; ++i) k4[i] = kr[i];
    __syncthreads();

    const float scale = 0.17677669529663687f;   // 1/sqrt(32)
    #pragma unroll 4
    for (int j = 0; j < UU; ++j) {
        float ds = 0.f;
        #pragma unroll
        for (int i = 0; i < 8; ++i) {
            float4 qv = *(const float4*)&qs[j * 32 + 4 * i];   // broadcast
            ds = fmaf(qv.x, k4[i].x, ds);
            ds = fmaf(qv.y, k4[i].y, ds);
            ds = fmaf(qv.z, k4[i].z, ds);
            ds = fmaf(qv.w, k4[i].w, ds);
        }
        sc[j * 256 + t] = ds * scale;
    }
    __syncthreads();

    int j8 = t >> 5, d = t & 31;
    #pragma unroll
    for (int g = 0; g < 5; ++g) {
        int j = g * 8 + j8;
        float4 a = *(const float4*)&sc[j * 256 + 4 * d];
        float4 b = *(const float4*)&sc[j * 256 + 128 + 4 * d];
        float m = fmaxf(fmaxf(fmaxf(a.x, a.y), fmaxf(a.z, a.w)),
                        fmaxf(fmaxf(b.x, b.y), fmaxf(b.z, b.w)));
        #pragma unroll
        for (int off = 16; off > 0; off >>= 1)
            m = fmaxf(m, __shfl_down(m, off, 64));
        if (d == 0) msh[j] = m;
    }
    __syncthreads();

    #pragma unroll 8
    for (int i = t; i < UU * 256; i += 256) {
        int j = i >> 8;
        sc[i] = __expf(sc[i] - msh[j]);
    }
    __syncthreads();

    int pq = bh * NSL + sl;

    #pragma unroll
    for (int g = 0; g < 5; ++g) {
        int j = g * 8 + j8;
        float4 a = *(const float4*)&sc[j * 256 + 4 * d];
        float4 b = *(const float4*)&sc[j * 256 + 128 + 4 * d];
        float s = a.x + a.y + a.z + a.w + b.x + b.y + b.z + b.w;
        #pragma unroll
        for (int off = 16; off > 0; off >>= 1)
            s += __shfl_down(s, off, 64);
        if (d == 0) { sP[pq * UU + j] = s; mP[pq * UU + j] = msh[j]; }
    }

    const float* vbase = vb + ((size_t)(bh * LL + l0) << 5) + d;
    float acc[5] = {0.f, 0.f, 0.f, 0.f, 0.f};
    #pragma unroll 4
    for (int i = 0; i < 64; ++i) {
        float v0 = vbase[(4 * i + 0) << 5];
        float v1 = vbase[(4 * i + 1) << 5];
        float v2 = vbase[(4 * i + 2) << 5];
        float v3 = vbase[(4 * i + 3) << 5];
        #pragma unroll
        for (int g = 0; g < 5; ++g) {
            float4 e4 = *(const float4*)&sc[(g * 8 + j8) * 256 + 4 * i];
            acc[g] = fmaf(e4.x, v0, acc[g]);
            acc[g] = fmaf(e4.y, v1, acc[g]);
            acc[g] = fmaf(e4.z, v2, acc[g]);
            acc[g] = fmaf(e4.w, v3, acc[g]);
        }
    }
    #pragma unroll
    for (int g = 0; g < 5; ++g)
        OP[((size_t)pq * UU + g * 8 + j8) * 32 + d] = acc[g];
}

// ---------------------------------------------------------------------------
// fillcomb: ctx bf16 = vmean broadcast; scattered (top) rows get the merged
// softmax update (combine logic inline via jidx rank byte). grid 8192 x 256.
// ---------------------------------------------------------------------------
__global__ __launch_bounds__(256)
void fillcomb_k(const float* __restrict__ vme, const uchar_t* __restrict__ jidx,
                const float* __restrict__ mP, const float* __restrict__ sP,
                const float* __restrict__ OP, ushort_t* __restrict__ ctxb)
{
    int tid = blockIdx.x * 256 + threadIdx.x;   // over BL*DM/2 pairs
    int pr   = tid & 127;
    int rowi = tid >> 7;          // b*2048 + l
    int b    = rowi >> 11;
    int hh   = pr >> 4;
    int j    = (int)jidx[(size_t)rowi * 8 + hh];

    float v0, v1;
    if (j == 0) {
        v0 = vme[(b << 8) + pr * 2];
        v1 = vme[(b << 8) + pr * 2 + 1];
    } else {
        int jj = j - 1;
        int bh = b * 8 + hh;
        int d0 = (pr * 2) & 31;
        float M = -3e38f;
        #pragma unroll
        for (int q = 0; q < NSL; ++q) M = fmaxf(M, mP[(bh * NSL + q) * UU + jj]);
        float S = 0.f, O0 = 0.f, O1 = 0.f;
        #pragma unroll
        for (int q = 0; q < NSL; ++q) {
            float wgt = __expf(mP[(bh * NSL + q) * UU + jj] - M);
            S  = fmaf(sP[(bh * NSL + q) * UU + jj], wgt, S);
            O0 = fmaf(OP[((size_t)(bh * NSL + q) * UU + jj) * 32 + d0], wgt, O0);
            O1 = fmaf(OP[((size_t)(bh * NSL + q) * UU + jj) * 32 + d0 + 1], wgt, O1);
        }
        v0 = O0 / S;
        v1 = O1 / S;
    }
    ((unsigned int*)ctxb)[tid] = (unsigned int)f2b(v0) | ((unsigned int)f2b(v1) << 16);
}

extern "C" void kernel_launch(void* const* d_in, const int* in_sizes, int n_in,
                              void* d_out, int out_size, void* d_ws, size_t ws_size,
                              hipStream_t stream)
{
    const float* x    = (const float*)d_in[0];
    const int*   idx  = (const int*)  d_in[1];
    const float* w_in = (const float*)d_in[2];
    const float* b_in = (const float*)d_in[3];
    const float* wq   = (const float*)d_in[4];
    const float* bq   = (const float*)d_in[5];
    const float* wk   = (const float*)d_in[6];
    const float* bk   = (const float*)d_in[7];
    const float* wv   = (const float*)d_in[8];
    const float* bv   = (const float*)d_in[9];
    const float* wo   = (const float*)d_in[10];
    const float* bo   = (const float*)d_in[11];
    const float* wf1  = (const float*)d_in[12];
    const float* bf1  = (const float*)d_in[13];
    const float* wf2  = (const float*)d_in[14];
    const float* bf2  = (const float*)d_in[15];
    const float* g1   = (const float*)d_in[16];
    const float* be1  = (const float*)d_in[17];
    const float* g2   = (const float*)d_in[18];
    const float* be2  = (const float*)d_in[19];
    const float* wfc1 = (const float*)d_in[20];
    const float* bfc1 = (const float*)d_in[21];
    const float* wfc2 = (const float*)d_in[22];
    const float* bfc2 = (const float*)d_in[23];
    float* out = (float*)d_out;

    float* ws = (float*)d_ws;
    float*    h     = ws;                          // [0, 4194304)
    float*    qkv   = ws + 4194304;                // [4194304, 16777216)
    float*    qb    = qkv;
    float*    kb    = qkv + 4194304;
    float*    vb    = qkv + 8388608;
    // attn scratch region (4194304 floats), all dead outside attention phase
    float*    attnS = ws + 16777216;
    ushort_t* kT16  = (ushort_t*)attnS;            //   fl [0, 2097152): kT bf16
    float*    Mbuf  = attnS + 2097152;             //   fl [2097152, 2228224)
    float*    candv = attnS + 2228224;             //   20480
    int*      candi = (int*)(attnS + 2248704);     //   20480
    float*    vmeP  = attnS + 2269184;             //   16384
    float*    OP    = attnS + 2285568;             //   655360
    float*    mP    = attnS + 2940928;             //   20480
    float*    sP    = attnS + 2961408;             //   20480
    uchar_t*  jidx  = (uchar_t*)(attnS + 2981888); //   32768 fl (131072 bytes)
    // long-lived scratch — offsets in FLOATS
    float*    scr   = ws + 20971520;
    ushort_t* xb16  = (ushort_t*)scr;              //   fl [0, 262144)
    float*    vme   = scr + 262144;                //   fl [262144, 264192)
    int*      top   = (int*)(scr + 264192);        //   fl [264192, 266752)
    ushort_t* hb    = (ushort_t*)(scr + 266752);   //   fl [266752, 2363904)
    ushort_t* wqkvT = (ushort_t*)(scr + 2363904);  //   fl [2363904, 2560512)
    ushort_t* woT   = (ushort_t*)(scr + 2560512);  //   fl [2560512, 2626048)
    ushort_t* wf1T  = (ushort_t*)(scr + 2626048);  //   fl [2626048, 2888192)
    ushort_t* wf2T  = (ushort_t*)(scr + 2888192);  //   fl [2888192, 3150336)
    ushort_t* w_inT = (ushort_t*)(scr + 3150336);  //   fl [3150336, 3154432)
    float*    bqkv  = scr + 3154432;               //   fl [3154432, 3155968)
    ushort_t* ctxb  = (ushort_t*)qkv;              // aliases dead q
    ushort_t* ffbb  = (ushort_t*)(qkv + 2097152);  // aliases dead q/k/v

    dim3 blk(256);

    preproc_k<<<dim3(2062), blk, 0, stream>>>(
        wq, wk, wv, wo, wf1, wf2, w_in, bq, bk, bv, x,
        wqkvT, woT, wf1T, wf2T, w_inT, bqkv, xb16);

    gemm_mfma<0,3><<<dim3(BL/128, 2), blk, 0, stream>>>(
        xb16, w_inT, b_in, (void*)h, (void*)hb, BL, DM, 32);

    for (int i = 0; i < 2; ++i) {
        gemm_mfma<0,1><<<dim3(BL/128, 6), blk, 0, stream>>>(
            hb, wqkvT + (size_t)i*768*256, bqkv + i*768, (void*)qkv, (void*)kT16,
            BL, 768, DM);

        metric2_k<<<dim3(512), blk, 0, stream>>>(
            qb, kT16, idx + (size_t)i*LL*SS, Mbuf, (unsigned int*)jidx);
        topk1_k<<<dim3(128), blk, 0, stream>>>(Mbuf, candv, candi);
        topk2_k<<<dim3(BB*NH), blk, 0, stream>>>(candv, candi, top, jidx);
        vmeanp_k<<<dim3(512), blk, 0, stream>>>(vb, vmeP);
        vfin_k<<<dim3(8), blk, 0, stream>>>(vmeP, vme);
        attnupd_k<<<dim3(BB*NH*NSL), blk, 0, stream>>>(qb, kb, vb, top, mP, sP, OP);
        fillcomb_k<<<dim3(BL*DM/512), blk, 0, stream>>>(vme, jidx, mP, sP, OP, ctxb);

        // fused O-proj + residual + LN1
        gemmln_k<0><<<dim3(BL/32), blk, 0, stream>>>(
            ctxb, woT + (size_t)i*256*256, bo + i*DM, h, hb,
            g1 + i*DM, be1 + i*DM, DM,
            nullptr, nullptr, nullptr, nullptr, nullptr);

        gemm_mfma<1,2><<<dim3(BL/128, 8), blk, 0, stream>>>(
            hb, wf1T + (size_t)i*1024*256, bf1 + i*DFF, (void*)ffbb, nullptr, BL, DFF, DM);

        // fused FF2 + residual + LN2 (+ MLP head on the last layer)
        if (i == 1) {
            gemmln_k<1><<<dim3(BL/32), blk, 0, stream>>>(
                ffbb, wf2T + (size_t)i*256*1024, bf2 + i*DM, h, hb,
                g2 + i*DM, be2 + i*DM, DFF,
                wfc1, bfc1, wfc2, bfc2, out);
        } else {
            gemmln_k<0><<<dim3(BL/32), blk, 0, stream>>>(
                ffbb, wf2T + (size_t)i*256*1024, bf2 + i*DM, h, hb,
                g2 + i*DM, be2 + i*DM, DFF,
                nullptr, nullptr, nullptr, nullptr, nullptr);
        }
    }
}

// Round 12
// 503.065 us; speedup vs baseline: 1.1206x; 1.0216x over previous
//
#include <hip/hip_runtime.h>
#include <math.h>

#define BB 8
#define LL 2048
#define DM 256
#define NH 8
#define DH 32
#define DFF 1024
#define SS 40
#define UU 40
#define BL (BB*LL)   // 16384
#define NSL 8        // attnupd L-slices per (b,h)

typedef unsigned short ushort_t;
typedef unsigned char uchar_t;
typedef __attribute__((ext_vector_type(8))) short short8;
typedef __attribute__((ext_vector_type(4))) float f32x4;

__device__ inline ushort_t f2b(float f)
{
    unsigned int u = __float_as_uint(f);
    u += 0x7fff + ((u >> 16) & 1);      // round-to-nearest-even
    return (ushort_t)(u >> 16);
}

__device__ inline void gload16(const void* g, const void* l)
{
    __builtin_amdgcn_global_load_lds(
        (const __attribute__((address_space(1))) unsigned int*)g,
        (__attribute__((address_space(3))) unsigned int*)l, 16, 0, 0);
}

// ---------------------------------------------------------------------------
// bf16 MFMA GEMM, m97 structure. 128x128 tile, BK=32, 256 thr.
// OUT_MODE: 0 fp32 RM | 1 QKV scatter (fp32 q,k,v BHLD + bf16 kT[l][bh][d])
//           2 bf16 RM | 3 fp32 RM + bf16 RM into aux
// ---------------------------------------------------------------------------
template<int RELU, int OUT_MODE>
__global__ __launch_bounds__(256)
void gemm_mfma(const ushort_t* __restrict__ A, const ushort_t* __restrict__ Bt,
               const float* __restrict__ bias, void* __restrict__ Cout,
               void* __restrict__ aux, int M, int N, int K)
{
    __shared__ ushort_t Asl[128 * 32];
    __shared__ ushort_t Bsl[128 * 32];

    const int t    = threadIdx.x;
    const int lane = t & 63;
    const int wv   = t >> 6;
    const int row0 = blockIdx.x * 128;
    const int col0 = blockIdx.y * 128;
    const int wr   = (wv >> 1) * 64;
    const int wc   = (wv & 1) * 64;
    const int quad = lane >> 4;
    const int l16  = lane & 15;

    f32x4 acc[4][4];
    #pragma unroll
    for (int i = 0; i < 4; ++i)
        #pragma unroll
        for (int j = 0; j < 4; ++j)
            acc[i][j] = 0.f;

    for (int k0 = 0; k0 < K; k0 += 32) {
        __syncthreads();
        #pragma unroll
        for (int r = 0; r < 2; ++r) {
            int g = r * 256 + t;
            const ushort_t* ga = A  + (size_t)(row0 + (g >> 2)) * K + k0 + (g & 3) * 8;
            const ushort_t* gb = Bt + (size_t)(col0 + (g >> 2)) * K + k0 + (g & 3) * 8;
            int lbase = (r * 256 + wv * 64) * 16;
            gload16(ga, (const char*)Asl + lbase);
            gload16(gb, (const char*)Bsl + lbase);
        }
        __syncthreads();

        short8 af[4], bfr[4];
        #pragma unroll
        for (int mi = 0; mi < 4; ++mi)
            af[mi] = *(const short8*)&Asl[(wr + mi * 16 + l16) * 32 + quad * 8];
        #pragma unroll
        for (int ni = 0; ni < 4; ++ni)
            bfr[ni] = *(const short8*)&Bsl[(wc + ni * 16 + l16) * 32 + quad * 8];
        #pragma unroll
        for (int mi = 0; mi < 4; ++mi)
            #pragma unroll
            for (int ni = 0; ni < 4; ++ni)
                acc[mi][ni] = __builtin_amdgcn_mfma_f32_16x16x32_bf16(
                    af[mi], bfr[ni], acc[mi][ni], 0, 0, 0);
    }

    #pragma unroll
    for (int mi = 0; mi < 4; ++mi) {
        #pragma unroll
        for (int ni = 0; ni < 4; ++ni) {
            int col = col0 + wc + ni * 16 + l16;
            float bb = bias[col];
            #pragma unroll
            for (int r = 0; r < 4; ++r) {
                int row = row0 + wr + mi * 16 + quad * 4 + r;
                float v = acc[mi][ni][r] + bb;
                if (RELU) v = v > 0.f ? v : 0.f;
                if (OUT_MODE == 0) {
                    ((float*)Cout)[(size_t)row * N + col] = v;
                } else if (OUT_MODE == 1) {
                    int tensor = col >> 8;          // 0=q 1=k 2=v
                    int c2 = col & 255;
                    int b  = row >> 11, l = row & (LL - 1);
                    int hh = c2 >> 5,  dh = c2 & 31;
                    int bh = b * NH + hh;
                    size_t bi = (((size_t)bh * LL + l) << 5) + dh;
                    ((float*)Cout)[(size_t)tensor * (BB*NH*LL*DH) + bi] = v;
                    if (tensor == 1)   // kT[l][bh][d] bf16 for metric
                        ((ushort_t*)aux)[(((size_t)l << 6) + bh) * 32 + dh] = f2b(v);
                } else if (OUT_MODE == 2) {
                    ((ushort_t*)Cout)[(size_t)row * N + col] = f2b(v);
                } else {
                    ((float*)Cout)[(size_t)row * N + col] = v;
                    ((ushort_t*)aux)[(size_t)row * N + col] = f2b(v);
                }
            }
        }
    }
}

// ---------------------------------------------------------------------------
// Fused GEMM (Mx256, K param) + residual + LayerNorm (+ optional MLP head):
//   h = LN(h + A@Bt^T + bias) * g + beta ; writes h fp32 + hb bf16.
// 32x256 tile, grid M/32 = 512 blocks (2/CU), 4 waves (wave = 64 cols).
// ---------------------------------------------------------------------------
template<int HEAD>
__global__ __launch_bounds__(256)
void gemmln_k(const ushort_t* __restrict__ A, const ushort_t* __restrict__ Bt,
              const float* __restrict__ bias, float* __restrict__ h,
              ushort_t* __restrict__ hb, const float* __restrict__ g,
              const float* __restrict__ beta, int K,
              const float* __restrict__ w1, const float* __restrict__ b1,
              const float* __restrict__ w2, const float* __restrict__ b2,
              float* __restrict__ out)
{
    __shared__ ushort_t Asl[32 * 32];    // 2 KB
    __shared__ ushort_t Bsl[256 * 32];   // 16 KB
    __shared__ float rs[4][32], rs2[4][32];
    __shared__ float hrowS[256];

    const int t    = threadIdx.x;
    const int lane = t & 63;
    const int wv   = t >> 6;
    const int row0 = blockIdx.x * 32;
    const int wc   = wv * 64;
    const int quad = lane >> 4;
    const int l16  = lane & 15;

    f32x4 acc[2][4];
    #pragma unroll
    for (int i = 0; i < 2; ++i)
        #pragma unroll
        for (int j = 0; j < 4; ++j)
            acc[i][j] = 0.f;

    for (int k0 = 0; k0 < K; k0 += 32) {
        __syncthreads();
        if (wv < 2) {   // A tile: 32 rows x 32 k = 2 KB, waves 0-1
            const ushort_t* ga = A + (size_t)(row0 + (t >> 2)) * K + k0 + (t & 3) * 8;
            gload16(ga, (const char*)Asl + wv * 1024);
        }
        #pragma unroll
        for (int r = 0; r < 4; ++r) {   // B tile: 256 rows x 32 k = 16 KB
            int gg = r * 256 + t;
            const ushort_t* gb = Bt + (size_t)(gg >> 2) * K + k0 + (gg & 3) * 8;
            gload16(gb, (const char*)Bsl + (r * 256 + wv * 64) * 16);
        }
        __syncthreads();

        short8 af[2], bfr[4];
        #pragma unroll
        for (int mi = 0; mi < 2; ++mi)
            af[mi] = *(const short8*)&Asl[(mi * 16 + l16) * 32 + quad * 8];
        #pragma unroll
        for (int ni = 0; ni < 4; ++ni)
            bfr[ni] = *(const short8*)&Bsl[(wc + ni * 16 + l16) * 32 + quad * 8];
        #pragma unroll
        for (int mi = 0; mi < 2; ++mi)
            #pragma unroll
            for (int ni = 0; ni < 4; ++ni)
                acc[mi][ni] = __builtin_amdgcn_mfma_f32_16x16x32_bf16(
                    af[mi], bfr[ni], acc[mi][ni], 0, 0, 0);
    }

    float gcol[4], bcol[4];
    #pragma unroll
    for (int ni = 0; ni < 4; ++ni) {
        int col = wc + ni * 16 + l16;
        gcol[ni] = g[col];
        bcol[ni] = beta[col];
    }
    float ps[2][4], ps2[2][4];
    #pragma unroll
    for (int mi = 0; mi < 2; ++mi) {
        #pragma unroll
        for (int r = 0; r < 4; ++r) {
            int row = row0 + mi * 16 + quad * 4 + r;
            float s = 0.f, s2 = 0.f;
            #pragma unroll
            for (int ni = 0; ni < 4; ++ni) {
                int col = wc + ni * 16 + l16;
                float v = acc[mi][ni][r] + bias[col] + h[(size_t)row * DM + col];
                acc[mi][ni][r] = v;
                s += v;
                s2 += v * v;
            }
            ps[mi][r] = s;
            ps2[mi][r] = s2;
        }
    }
    #pragma unroll
    for (int off = 1; off < 16; off <<= 1) {
        #pragma unroll
        for (int mi = 0; mi < 2; ++mi)
            #pragma unroll
            for (int r = 0; r < 4; ++r) {
                ps[mi][r]  += __shfl_xor(ps[mi][r],  off, 16);
                ps2[mi][r] += __shfl_xor(ps2[mi][r], off, 16);
            }
    }
    if (l16 == 0) {
        #pragma unroll
        for (int mi = 0; mi < 2; ++mi)
            #pragma unroll
            for (int r = 0; r < 4; ++r) {
                int lrow = mi * 16 + quad * 4 + r;
                rs[wv][lrow]  = ps[mi][r];
                rs2[wv][lrow] = ps2[mi][r];
            }
    }
    __syncthreads();

    #pragma unroll
    for (int mi = 0; mi < 2; ++mi) {
        #pragma unroll
        for (int r = 0; r < 4; ++r) {
            int lrow = mi * 16 + quad * 4 + r;
            int row  = row0 + lrow;
            float tot  = rs[0][lrow] + rs[1][lrow] + rs[2][lrow] + rs[3][lrow];
            float tot2 = rs2[0][lrow] + rs2[1][lrow] + rs2[2][lrow] + rs2[3][lrow];
            float mean = tot * (1.f / (float)DM);
            float var  = tot2 * (1.f / (float)DM) - mean * mean;
            float inv  = 1.0f / sqrtf(var + 1e-5f);
            #pragma unroll
            for (int ni = 0; ni < 4; ++ni) {
                int col = wc + ni * 16 + l16;
                float val = (acc[mi][ni][r] - mean) * inv * gcol[ni] + bcol[ni];
                h[(size_t)row * DM + col]  = val;
                hb[(size_t)row * DM + col] = f2b(val);
                if (HEAD && lrow == 31) hrowS[col] = val;   // last row of block
            }
        }
    }

    if (HEAD) {
        __syncthreads();
        // blocks covering row (b*2048 + 2047): blockIdx = b*64 + 63
        if ((blockIdx.x & 63) == 63 && t < 64) {
            int b = blockIdx.x >> 6;
            float s = 0.f;
            for (int kk = 0; kk < DM; ++kk)
                s = fmaf(hrowS[kk], w1[kk * 64 + t], s);
            s += b1[t];
            s = s > 0.f ? s : 0.f;
            float contrib = s * w2[t];
            #pragma unroll
            for (int off = 32; off > 0; off >>= 1)
                contrib += __shfl_down(contrib, off, 64);
            if (t == 0) out[b] = contrib + b2[0];
        }
    }
}

// ---------------------------------------------------------------------------
// fused preproc: all weight transposes+cvt, bias pack, x cvt in ONE dispatch.
// ---------------------------------------------------------------------------
__device__ inline void tcvt_dev(float (*tile)[33], const float* __restrict__ src,
                                ushort_t* __restrict__ dst, int K, int N,
                                int matStride, int bi)
{
    int tilesN = N >> 5;
    int tpm = (K >> 5) * tilesN;
    int m   = bi / tpm;
    int tid = bi % tpm;
    int k0 = (tid / tilesN) << 5, n0 = (tid % tilesN) << 5;
    const float* s = src + (size_t)m * K * N;
    ushort_t*    d = dst + (size_t)m * matStride;
    int r = threadIdx.x >> 5, c = threadIdx.x & 31;
    #pragma unroll
    for (int i = 0; i < 4; ++i)
        tile[r + 8 * i][c] = s[(size_t)(k0 + r + 8 * i) * N + n0 + c];
    __syncthreads();
    #pragma unroll
    for (int i = 0; i < 4; ++i)
        d[(size_t)(n0 + r + 8 * i) * K + k0 + c] = f2b(tile[c][r + 8 * i]);
}

__global__ __launch_bounds__(256)
void preproc_k(const float* __restrict__ wq, const float* __restrict__ wk,
               const float* __restrict__ wv, const float* __restrict__ wo,
               const float* __restrict__ wf1, const float* __restrict__ wf2,
               const float* __restrict__ w_in,
               const float* __restrict__ bq, const float* __restrict__ bk,
               const float* __restrict__ bv, const float* __restrict__ x,
               ushort_t* __restrict__ wqkvT, ushort_t* __restrict__ woT,
               ushort_t* __restrict__ wf1T, ushort_t* __restrict__ wf2T,
               ushort_t* __restrict__ w_inT, float* __restrict__ bqkv,
               ushort_t* __restrict__ xb16)
{
    __shared__ float tile[32][33];
    int b = blockIdx.x;
    if (b < 512) {
        int which = b >> 7, lb = b & 127;
        const float* src = which == 0 ? wq : which == 1 ? wk : which == 2 ? wv : wo;
        ushort_t* dst = which == 0 ? wqkvT : which == 1 ? wqkvT + 65536
                       : which == 2 ? wqkvT + 131072 : woT;
        int stride = which == 3 ? 65536 : 768 * 256;
        tcvt_dev(tile, src, dst, DM, DM, stride, lb);
    } else if (b < 1024) {
        tcvt_dev(tile, wf1, wf1T, DM, DFF, 1024 * 256, b - 512);
    } else if (b < 1536) {
        tcvt_dev(tile, wf2, wf2T, DFF, DM, 256 * 1024, b - 1024);
    } else if (b < 1544) {
        tcvt_dev(tile, w_in, w_inT, 32, DM, 256 * 32, b - 1536);
    } else if (b < 1550) {
        int t = (b - 1544) * 256 + threadIdx.x;
        int i = t / 768, j = t % 768;
        const float* s = j < 256 ? bq : (j < 512 ? bk : bv);
        bqkv[t] = s[i * 256 + (j & 255)];
    } else {
        int tid = (b - 1550) * 256 + threadIdx.x;
        float4 v = ((const float4*)x)[tid];
        unsigned int lo = f2b(v.x) | ((unsigned int)f2b(v.y) << 16);
        unsigned int hi = f2b(v.z) | ((unsigned int)f2b(v.w) << 16);
        ((uint2*)xb16)[tid] = make_uint2(lo, hi);
    }
}

// ---------------------------------------------------------------------------
// metric v3: lane = bh, wave = one query position l. kT[l][bh][d] reads are
// fully coalesced. Also zeroes jidx for its 4 l positions. grid 512 x 256.
// ---------------------------------------------------------------------------
__global__ __launch_bounds__(256)
void metric2_k(const float* __restrict__ qb, const ushort_t* __restrict__ kT,
               const int* __restrict__ idx, float* __restrict__ Mout,
               unsigned int* __restrict__ jidx32)
{
    __shared__ float mst[64][5];
    int t = threadIdx.x;
    int w = t >> 6, lane = t & 63;
    int l = blockIdx.x * 4 + w;

    // zero jidx for (b, l in this block's range): 8b x 4l x 8h bytes = 64 uints
    if (t < 64) {
        int zb = t >> 3, sel = t & 7;
        int zl = blockIdx.x * 4 + (sel >> 1), half = sel & 1;
        jidx32[(size_t)(zb * LL + zl) * 2 + half] = 0;
    }

    const float4* qr = (const float4*)(qb + ((size_t)(lane * LL + l) << 5));
    float4 q[8];
    #pragma unroll
    for (int i = 0; i < 8; ++i) q[i] = qr[i];

    int r40 = idx[l * SS + (lane < SS ? lane : SS - 1)];

    float mx = -3e38f, sm = 0.f;
    for (int s = 0; s < SS; ++s) {
        int r = __shfl(r40, s, 64);
        const uint4* kr = (const uint4*)(kT + (((size_t)r << 6) + lane) * 32);
        float d = 0.f;
        #pragma unroll
        for (int ww = 0; ww < 4; ++ww) {
            uint4 kv = kr[ww];
            float4 qa = q[2 * ww], qb2 = q[2 * ww + 1];
            d = fmaf(__uint_as_float(kv.x << 16),         qa.x, d);
            d = fmaf(__uint_as_float(kv.x & 0xffff0000u), qa.y, d);
            d = fmaf(__uint_as_float(kv.y << 16),         qa.z, d);
            d = fmaf(__uint_as_float(kv.y & 0xffff0000u), qa.w, d);
            d = fmaf(__uint_as_float(kv.z << 16),         qb2.x, d);
            d = fmaf(__uint_as_float(kv.z & 0xffff0000u), qb2.y, d);
            d = fmaf(__uint_as_float(kv.w << 16),         qb2.z, d);
            d = fmaf(__uint_as_float(kv.w & 0xffff0000u), qb2.w, d);
        }
        mx = fmaxf(mx, d);
        sm += d;
    }
    mst[lane][w] = mx - sm * (1.0f / (float)LL);
    __syncthreads();

    int bh = t >> 2, ls = t & 3;
    Mout[(size_t)bh * LL + blockIdx.x * 4 + ls] = mst[bh][ls];
}

// ---------------------------------------------------------------------------
// topkf: fused top-40. grid 64 x 512 threads: 8 waves/block, wave w runs the
// stage-1 slice argmax for slice w (identical parallelism to old topk1's 512
// waves), then in-LDS rank-select (old topk2). Writes top + jidx rank byte.
// ---------------------------------------------------------------------------
__global__ __launch_bounds__(512)
void topkf_k(const float* __restrict__ Mout, int* __restrict__ top,
             uchar_t* __restrict__ jidx)
{
    __shared__ float cvS[320];
    __shared__ int   ciS[320];
    int bh = blockIdx.x;
    int t  = threadIdx.x;
    int lane = t & 63, w = t >> 6;   // w = slice 0..7
    int l0 = w << 8;

    float v[4];
    #pragma unroll
    for (int i = 0; i < 4; ++i)
        v[i] = Mout[(size_t)bh * LL + l0 + i * 64 + lane];

    for (int r = 0; r < UU; ++r) {
        float bv = -3e38f; int bi = 1 << 30;
        #pragma unroll
        for (int i = 0; i < 4; ++i) {
            int idx = l0 + i * 64 + lane;
            if (v[i] > bv || (v[i] == bv && idx < bi)) { bv = v[i]; bi = idx; }
        }
        #pragma unroll
        for (int off = 32; off > 0; off >>= 1) {
            float ov = __shfl_down(bv, off, 64);
            int   oi = __shfl_down(bi, off, 64);
            if (ov > bv || (ov == bv && oi < bi)) { bv = ov; bi = oi; }
        }
        bv = __shfl(bv, 0, 64);
        bi = __shfl(bi, 0, 64);
        if (lane == 0) { cvS[w * UU + r] = bv; ciS[w * UU + r] = bi; }
        int rel = bi - l0;
        if ((rel & 63) == lane) v[rel >> 6] = -3e38f;
    }
    __syncthreads();

    for (int c = t; c < 320; c += 512) {
        float mv = cvS[c]; int mi = ciS[c];
        int rank = 0;
        for (int j = 0; j < 320; ++j)
            rank += (cvS[j] > mv) || (cvS[j] == mv && ciS[j] < mi);
        if (rank < UU) {
            top[bh * UU + rank] = mi;
            int b = bh >> 3, hh = bh & 7;
            jidx[(size_t)(b * LL + mi) * 8 + hh] = (uchar_t)(rank + 1);
        }
    }
}

// ---------------------------------------------------------------------------
// attnupd: block = bh*NSL + slice (512 blocks), 256 l per slice.
// Also emits per-slice V column sums (vmeanP) — V is streamed anyway.
// ---------------------------------------------------------------------------
__global__ __launch_bounds__(256)
void attnupd_k(const float* __restrict__ qb, const float* __restrict__ kb,
               const float* __restrict__ vb, const int* __restrict__ top,
               float* __restrict__ mP, float* __restrict__ sP,
               float* __restrict__ OP, float* __restrict__ vmeanP)
{
    __shared__ float qs[UU * 32];        // 5 KB
    __shared__ float sc[UU * 256];       // 40 KB
    __shared__ float msh[UU];

    int blk = blockIdx.x;
    int sl  = blk & (NSL - 1);
    int bh  = blk >> 3;
    int t   = threadIdx.x;
    int l0  = sl << 8;

    for (int i = t; i < UU * 32; i += 256) {
        int j = i >> 5, dd = i & 31;
        qs[i] = qb[((size_t)(bh * LL + top[bh * UU + j]) << 5) + dd];
    }

    const float4* kr = (const float4*)(kb + ((size_t)(bh * LL + l0 + t) << 5));
    float4 k4[8];
    #pragma unroll
    for (int i = 0; i < 8; ++i) k4[i] = kr[i];
    __syncthreads();

    const float scale = 0.17677669529663687f;   // 1/sqrt(32)
    #pragma unroll 4
    for (int j = 0; j < UU; ++j) {
        float ds = 0.f;
        #pragma unroll
        for (int i = 0; i < 8; ++i) {
            float4 qv = *(const float4*)&qs[j * 32 + 4 * i];   // broadcast
            ds = fmaf(qv.x, k4[i].x, ds);
            ds = fmaf(qv.y, k4[i].y, ds);
            ds = fmaf(qv.z, k4[i].z, ds);
            ds = fmaf(qv.w, k4[i].w, ds);
        }
        sc[j * 256 + t] = ds * scale;
    }
    __syncthreads();

    int j8 = t >> 5, d = t & 31;
    #pragma unroll
    for (int g = 0; g < 5; ++g) {
        int j = g * 8 + j8;
        float4 a = *(const float4*)&sc[j * 256 + 4 * d];
        float4 b = *(const float4*)&sc[j * 256 + 128 + 4 * d];
        float m = fmaxf(fmaxf(fmaxf(a.x, a.y), fmaxf(a.z, a.w)),
                        fmaxf(fmaxf(b.x, b.y), fmaxf(b.z, b.w)));
        #pragma unroll
        for (int off = 16; off > 0; off >>= 1)
            m = fmaxf(m, __shfl_down(m, off, 64));
        if (d == 0) msh[j] = m;
    }
    __syncthreads();

    #pragma unroll 8
    for (int i = t; i < UU * 256; i += 256) {
        int j = i >> 8;
        sc[i] = __expf(sc[i] - msh[j]);
    }
    __syncthreads();

    int pq = bh * NSL + sl;

    #pragma unroll
    for (int g = 0; g < 5; ++g) {
        int j = g * 8 + j8;
        float4 a = *(const float4*)&sc[j * 256 + 4 * d];
        float4 b = *(const float4*)&sc[j * 256 + 128 + 4 * d];
        float s = a.x + a.y + a.z + a.w + b.x + b.y + b.z + b.w;
        #pragma unroll
        for (int off = 16; off > 0; off >>= 1)
            s += __shfl_down(s, off, 64);
        if (d == 0) { sP[pq * UU + j] = s; mP[pq * UU + j] = msh[j]; }
    }

    const float* vbase = vb + ((size_t)(bh * LL + l0) << 5) + d;
    float acc[5] = {0.f, 0.f, 0.f, 0.f, 0.f};
    float vsum = 0.f;
    #pragma unroll 4
    for (int i = 0; i < 64; ++i) {
        float v0 = vbase[(4 * i + 0) << 5];
        float v1 = vbase[(4 * i + 1) << 5];
        float v2 = vbase[(4 * i + 2) << 5];
        float v3 = vbase[(4 * i + 3) << 5];
        vsum += v0 + v1 + v2 + v3;
        #pragma unroll
        for (int g = 0; g < 5; ++g) {
            float4 e4 = *(const float4*)&sc[(g * 8 + j8) * 256 + 4 * i];
            acc[g] = fmaf(e4.x, v0, acc[g]);
            acc[g] = fmaf(e4.y, v1, acc[g]);
            acc[g] = fmaf(e4.z, v2, acc[g]);
            acc[g] = fmaf(e4.w, v3, acc[g]);
        }
    }
    #pragma unroll
    for (int g = 0; g < 5; ++g)
        OP[((size_t)pq * UU + g * 8 + j8) * 32 + d] = acc[g];
    if (j8 == 0) vmeanP[pq * 32 + d] = vsum;
}

// ---------------------------------------------------------------------------
// fillcomb: ctx bf16 = vmean broadcast (8 slice partials summed inline, vfin
// folded); scattered (top) rows get the merged softmax update via jidx.
// ---------------------------------------------------------------------------
__global__ __launch_bounds__(256)
void fillcomb_k(const float* __restrict__ vmeanP, const uchar_t* __restrict__ jidx,
                const float* __restrict__ mP, const float* __restrict__ sP,
                const float* __restrict__ OP, ushort_t* __restrict__ ctxb)
{
    int tid = blockIdx.x * 256 + threadIdx.x;   // over BL*DM/2 pairs
    int pr   = tid & 127;
    int rowi = tid >> 7;          // b*2048 + l
    int b    = rowi >> 11;
    int hh   = pr >> 4;
    int bh   = b * 8 + hh;
    int d0   = (pr * 2) & 31;
    int j    = (int)jidx[(size_t)rowi * 8 + hh];

    float v0, v1;
    if (j == 0) {
        float s0 = 0.f, s1 = 0.f;
        #pragma unroll
        for (int q = 0; q < NSL; ++q) {
            s0 += vmeanP[(bh * NSL + q) * 32 + d0];
            s1 += vmeanP[(bh * NSL + q) * 32 + d0 + 1];
        }
        v0 = s0 * (1.f / (float)LL);
        v1 = s1 * (1.f / (float)LL);
    } else {
        int jj = j - 1;
        float M = -3e38f;
        #pragma unroll
        for (int q = 0; q < NSL; ++q) M = fmaxf(M, mP[(bh * NSL + q) * UU + jj]);
        float S = 0.f, O0 = 0.f, O1 = 0.f;
        #pragma unroll
        for (int q = 0; q < NSL; ++q) {
            float wgt = __expf(mP[(bh * NSL + q) * UU + jj] - M);
            S  = fmaf(sP[(bh * NSL + q) * UU + jj], wgt, S);
            O0 = fmaf(OP[((size_t)(bh * NSL + q) * UU + jj) * 32 + d0], wgt, O0);
            O1 = fmaf(OP[((size_t)(bh * NSL + q) * UU + jj) * 32 + d0 + 1], wgt, O1);
        }
        v0 = O0 / S;
        v1 = O1 / S;
    }
    ((unsigned int*)ctxb)[tid] = (unsigned int)f2b(v0) | ((unsigned int)f2b(v1) << 16);
}

extern "C" void kernel_launch(void* const* d_in, const int* in_sizes, int n_in,
                              void* d_out, int out_size, void* d_ws, size_t ws_size,
                              hipStream_t stream)
{
    const float* x    = (const float*)d_in[0];
    const int*   idx  = (const int*)  d_in[1];
    const float* w_in = (const float*)d_in[2];
    const float* b_in = (const float*)d_in[3];
    const float* wq   = (const float*)d_in[4];
    const float* bq   = (const float*)d_in[5];
    const float* wk   = (const float*)d_in[6];
    const float* bk   = (const float*)d_in[7];
    const float* wv   = (const float*)d_in[8];
    const float* bv   = (const float*)d_in[9];
    const float* wo   = (const float*)d_in[10];
    const float* bo   = (const float*)d_in[11];
    const float* wf1  = (const float*)d_in[12];
    const float* bf1  = (const float*)d_in[13];
    const float* wf2  = (const float*)d_in[14];
    const float* bf2  = (const float*)d_in[15];
    const float* g1   = (const float*)d_in[16];
    const float* be1  = (const float*)d_in[17];
    const float* g2   = (const float*)d_in[18];
    const float* be2  = (const float*)d_in[19];
    const float* wfc1 = (const float*)d_in[20];
    const float* bfc1 = (const float*)d_in[21];
    const float* wfc2 = (const float*)d_in[22];
    const float* bfc2 = (const float*)d_in[23];
    float* out = (float*)d_out;

    float* ws = (float*)d_ws;
    float*    h     = ws;                          // [0, 4194304)
    float*    qkv   = ws + 4194304;                // [4194304, 16777216)
    float*    qb    = qkv;
    float*    kb    = qkv + 4194304;
    float*    vb    = qkv + 8388608;
    // attn scratch region (4194304 floats), all dead outside attention phase
    float*    attnS = ws + 16777216;
    ushort_t* kT16  = (ushort_t*)attnS;            //   fl [0, 2097152): kT bf16
    float*    Mbuf  = attnS + 2097152;             //   fl [2097152, 2228224)
    float*    vmeP  = attnS + 2269184;             //   16384
    float*    OP    = attnS + 2285568;             //   655360
    float*    mP    = attnS + 2940928;             //   20480
    float*    sP    = attnS + 2961408;             //   20480
    uchar_t*  jidx  = (uchar_t*)(attnS + 2981888); //   32768 fl (131072 bytes)
    // long-lived scratch — offsets in FLOATS
    float*    scr   = ws + 20971520;
    ushort_t* xb16  = (ushort_t*)scr;              //   fl [0, 262144)
    int*      top   = (int*)(scr + 264192);        //   fl [264192, 266752)
    ushort_t* hb    = (ushort_t*)(scr + 266752);   //   fl [266752, 2363904)
    ushort_t* wqkvT = (ushort_t*)(scr + 2363904);  //   fl [2363904, 2560512)
    ushort_t* woT   = (ushort_t*)(scr + 2560512);  //   fl [2560512, 2626048)
    ushort_t* wf1T  = (ushort_t*)(scr + 2626048);  //   fl [2626048, 2888192)
    ushort_t* wf2T  = (ushort_t*)(scr + 2888192);  //   fl [2888192, 3150336)
    ushort_t* w_inT = (ushort_t*)(scr + 3150336);  //   fl [3150336, 3154432)
    float*    bqkv  = scr + 3154432;               //   fl [3154432, 3155968)
    ushort_t* ctxb  = (ushort_t*)qkv;              // aliases dead q
    ushort_t* ffbb  = (ushort_t*)(qkv + 2097152);  // aliases dead q/k/v

    dim3 blk(256);

    preproc_k<<<dim3(2062), blk, 0, stream>>>(
        wq, wk, wv, wo, wf1, wf2, w_in, bq, bk, bv, x,
        wqkvT, woT, wf1T, wf2T, w_inT, bqkv, xb16);

    gemm_mfma<0,3><<<dim3(BL/128, 2), blk, 0, stream>>>(
        xb16, w_inT, b_in, (void*)h, (void*)hb, BL, DM, 32);

    for (int i = 0; i < 2; ++i) {
        gemm_mfma<0,1><<<dim3(BL/128, 6), blk, 0, stream>>>(
            hb, wqkvT + (size_t)i*768*256, bqkv + i*768, (void*)qkv, (void*)kT16,
            BL, 768, DM);

        metric2_k<<<dim3(512), blk, 0, stream>>>(
            qb, kT16, idx + (size_t)i*LL*SS, Mbuf, (unsigned int*)jidx);
        topkf_k<<<dim3(BB*NH), dim3(512), 0, stream>>>(Mbuf, top, jidx);
        attnupd_k<<<dim3(BB*NH*NSL), blk, 0, stream>>>(qb, kb, vb, top, mP, sP, OP, vmeP);
        fillcomb_k<<<dim3(BL*DM/512), blk, 0, stream>>>(vmeP, jidx, mP, sP, OP, ctxb);

        // fused O-proj + residual + LN1
        gemmln_k<0><<<dim3(BL/32), blk, 0, stream>>>(
            ctxb, woT + (size_t)i*256*256, bo + i*DM, h, hb,
            g1 + i*DM, be1 + i*DM, DM,
            nullptr, nullptr, nullptr, nullptr, nullptr);

        gemm_mfma<1,2><<<dim3(BL/128, 8), blk, 0, stream>>>(
            hb, wf1T + (size_t)i*1024*256, bf1 + i*DFF, (void*)ffbb, nullptr, BL, DFF, DM);

        // fused FF2 + residual + LN2 (+ MLP head on the last layer)
        if (i == 1) {
            gemmln_k<1><<<dim3(BL/32), blk, 0, stream>>>(
                ffbb, wf2T + (size_t)i*256*1024, bf2 + i*DM, h, hb,
                g2 + i*DM, be2 + i*DM, DFF,
                wfc1, bfc1, wfc2, bfc2, out);
        } else {
            gemmln_k<0><<<dim3(BL/32), blk, 0, stream>>>(
                ffbb, wf2T + (size_t)i*256*1024, bf2 + i*DM, h, hb,
                g2 + i*DM, be2 + i*DM, DFF,
                nullptr, nullptr, nullptr, nullptr, nullptr);
        }
    }
}

// Round 13
// 474.078 us; speedup vs baseline: 1.1891x; 1.0611x over previous
//
#include <hip/hip_runtime.h>
#include <math.h>

#define BB 8
#define LL 2048
#define DM 256
#define NH 8
#define DH 32
#define DFF 1024
#define SS 40
#define UU 40
#define BL (BB*LL)   // 16384
#define NSL 8        // attnupd L-slices per (b,h)

// attnupd LDS layout constants
#define SCP 260      // sc row stride (floats) — breaks 16-way bank aliasing
#define KP  40       // k/q row stride (ushorts) — 16B-aligned rows for b128
#define VP  34       // v row stride (ushorts) — ~2-way for column u16 gathers

typedef unsigned short ushort_t;
typedef unsigned char uchar_t;
typedef __attribute__((ext_vector_type(8))) short short8;
typedef __attribute__((ext_vector_type(4))) float f32x4;

__device__ inline ushort_t f2b(float f)
{
    unsigned int u = __float_as_uint(f);
    u += 0x7fff + ((u >> 16) & 1);      // round-to-nearest-even
    return (ushort_t)(u >> 16);
}

__device__ inline void gload16(const void* g, const void* l)
{
    __builtin_amdgcn_global_load_lds(
        (const __attribute__((address_space(1))) unsigned int*)g,
        (__attribute__((address_space(3))) unsigned int*)l, 16, 0, 0);
}

// ---------------------------------------------------------------------------
// bf16 MFMA GEMM, m97 structure. 128x128 tile, BK=32, 256 thr.
// OUT_MODE: 0 fp32 RM | 1 QKV scatter (fp32 q,k,v BHLD + bf16 kT[l][bh][d])
//           2 bf16 RM | 3 fp32 RM + bf16 RM into aux
// ---------------------------------------------------------------------------
template<int RELU, int OUT_MODE>
__global__ __launch_bounds__(256)
void gemm_mfma(const ushort_t* __restrict__ A, const ushort_t* __restrict__ Bt,
               const float* __restrict__ bias, void* __restrict__ Cout,
               void* __restrict__ aux, int M, int N, int K)
{
    __shared__ ushort_t Asl[128 * 32];
    __shared__ ushort_t Bsl[128 * 32];

    const int t    = threadIdx.x;
    const int lane = t & 63;
    const int wv   = t >> 6;
    const int row0 = blockIdx.x * 128;
    const int col0 = blockIdx.y * 128;
    const int wr   = (wv >> 1) * 64;
    const int wc   = (wv & 1) * 64;
    const int quad = lane >> 4;
    const int l16  = lane & 15;

    f32x4 acc[4][4];
    #pragma unroll
    for (int i = 0; i < 4; ++i)
        #pragma unroll
        for (int j = 0; j < 4; ++j)
            acc[i][j] = 0.f;

    for (int k0 = 0; k0 < K; k0 += 32) {
        __syncthreads();
        #pragma unroll
        for (int r = 0; r < 2; ++r) {
            int g = r * 256 + t;
            const ushort_t* ga = A  + (size_t)(row0 + (g >> 2)) * K + k0 + (g & 3) * 8;
            const ushort_t* gb = Bt + (size_t)(col0 + (g >> 2)) * K + k0 + (g & 3) * 8;
            int lbase = (r * 256 + wv * 64) * 16;
            gload16(ga, (const char*)Asl + lbase);
            gload16(gb, (const char*)Bsl + lbase);
        }
        __syncthreads();

        short8 af[4], bfr[4];
        #pragma unroll
        for (int mi = 0; mi < 4; ++mi)
            af[mi] = *(const short8*)&Asl[(wr + mi * 16 + l16) * 32 + quad * 8];
        #pragma unroll
        for (int ni = 0; ni < 4; ++ni)
            bfr[ni] = *(const short8*)&Bsl[(wc + ni * 16 + l16) * 32 + quad * 8];
        #pragma unroll
        for (int mi = 0; mi < 4; ++mi)
            #pragma unroll
            for (int ni = 0; ni < 4; ++ni)
                acc[mi][ni] = __builtin_amdgcn_mfma_f32_16x16x32_bf16(
                    af[mi], bfr[ni], acc[mi][ni], 0, 0, 0);
    }

    #pragma unroll
    for (int mi = 0; mi < 4; ++mi) {
        #pragma unroll
        for (int ni = 0; ni < 4; ++ni) {
            int col = col0 + wc + ni * 16 + l16;
            float bb = bias[col];
            #pragma unroll
            for (int r = 0; r < 4; ++r) {
                int row = row0 + wr + mi * 16 + quad * 4 + r;
                float v = acc[mi][ni][r] + bb;
                if (RELU) v = v > 0.f ? v : 0.f;
                if (OUT_MODE == 0) {
                    ((float*)Cout)[(size_t)row * N + col] = v;
                } else if (OUT_MODE == 1) {
                    int tensor = col >> 8;          // 0=q 1=k 2=v
                    int c2 = col & 255;
                    int b  = row >> 11, l = row & (LL - 1);
                    int hh = c2 >> 5,  dh = c2 & 31;
                    int bh = b * NH + hh;
                    size_t bi = (((size_t)bh * LL + l) << 5) + dh;
                    ((float*)Cout)[(size_t)tensor * (BB*NH*LL*DH) + bi] = v;
                    if (tensor == 1)   // kT[l][bh][d] bf16 for metric
                        ((ushort_t*)aux)[(((size_t)l << 6) + bh) * 32 + dh] = f2b(v);
                } else if (OUT_MODE == 2) {
                    ((ushort_t*)Cout)[(size_t)row * N + col] = f2b(v);
                } else {
                    ((float*)Cout)[(size_t)row * N + col] = v;
                    ((ushort_t*)aux)[(size_t)row * N + col] = f2b(v);
                }
            }
        }
    }
}

// ---------------------------------------------------------------------------
// Fused GEMM (Mx256, K param) + residual + LayerNorm (+ optional MLP head):
//   h = LN(h + A@Bt^T + bias) * g + beta ; writes h fp32 + hb bf16.
// 32x256 tile, grid M/32 = 512 blocks (2/CU), 4 waves (wave = 64 cols).
// ---------------------------------------------------------------------------
template<int HEAD>
__global__ __launch_bounds__(256)
void gemmln_k(const ushort_t* __restrict__ A, const ushort_t* __restrict__ Bt,
              const float* __restrict__ bias, float* __restrict__ h,
              ushort_t* __restrict__ hb, const float* __restrict__ g,
              const float* __restrict__ beta, int K,
              const float* __restrict__ w1, const float* __restrict__ b1,
              const float* __restrict__ w2, const float* __restrict__ b2,
              float* __restrict__ out)
{
    __shared__ ushort_t Asl[32 * 32];    // 2 KB
    __shared__ ushort_t Bsl[256 * 32];   // 16 KB
    __shared__ float rs[4][32], rs2[4][32];
    __shared__ float hrowS[256];

    const int t    = threadIdx.x;
    const int lane = t & 63;
    const int wv   = t >> 6;
    const int row0 = blockIdx.x * 32;
    const int wc   = wv * 64;
    const int quad = lane >> 4;
    const int l16  = lane & 15;

    f32x4 acc[2][4];
    #pragma unroll
    for (int i = 0; i < 2; ++i)
        #pragma unroll
        for (int j = 0; j < 4; ++j)
            acc[i][j] = 0.f;

    for (int k0 = 0; k0 < K; k0 += 32) {
        __syncthreads();
        if (wv < 2) {   // A tile: 32 rows x 32 k = 2 KB, waves 0-1
            const ushort_t* ga = A + (size_t)(row0 + (t >> 2)) * K + k0 + (t & 3) * 8;
            gload16(ga, (const char*)Asl + wv * 1024);
        }
        #pragma unroll
        for (int r = 0; r < 4; ++r) {   // B tile: 256 rows x 32 k = 16 KB
            int gg = r * 256 + t;
            const ushort_t* gb = Bt + (size_t)(gg >> 2) * K + k0 + (gg & 3) * 8;
            gload16(gb, (const char*)Bsl + (r * 256 + wv * 64) * 16);
        }
        __syncthreads();

        short8 af[2], bfr[4];
        #pragma unroll
        for (int mi = 0; mi < 2; ++mi)
            af[mi] = *(const short8*)&Asl[(mi * 16 + l16) * 32 + quad * 8];
        #pragma unroll
        for (int ni = 0; ni < 4; ++ni)
            bfr[ni] = *(const short8*)&Bsl[(wc + ni * 16 + l16) * 32 + quad * 8];
        #pragma unroll
        for (int mi = 0; mi < 2; ++mi)
            #pragma unroll
            for (int ni = 0; ni < 4; ++ni)
                acc[mi][ni] = __builtin_amdgcn_mfma_f32_16x16x32_bf16(
                    af[mi], bfr[ni], acc[mi][ni], 0, 0, 0);
    }

    float gcol[4], bcol[4];
    #pragma unroll
    for (int ni = 0; ni < 4; ++ni) {
        int col = wc + ni * 16 + l16;
        gcol[ni] = g[col];
        bcol[ni] = beta[col];
    }
    float ps[2][4], ps2[2][4];
    #pragma unroll
    for (int mi = 0; mi < 2; ++mi) {
        #pragma unroll
        for (int r = 0; r < 4; ++r) {
            int row = row0 + mi * 16 + quad * 4 + r;
            float s = 0.f, s2 = 0.f;
            #pragma unroll
            for (int ni = 0; ni < 4; ++ni) {
                int col = wc + ni * 16 + l16;
                float v = acc[mi][ni][r] + bias[col] + h[(size_t)row * DM + col];
                acc[mi][ni][r] = v;
                s += v;
                s2 += v * v;
            }
            ps[mi][r] = s;
            ps2[mi][r] = s2;
        }
    }
    #pragma unroll
    for (int off = 1; off < 16; off <<= 1) {
        #pragma unroll
        for (int mi = 0; mi < 2; ++mi)
            #pragma unroll
            for (int r = 0; r < 4; ++r) {
                ps[mi][r]  += __shfl_xor(ps[mi][r],  off, 16);
                ps2[mi][r] += __shfl_xor(ps2[mi][r], off, 16);
            }
    }
    if (l16 == 0) {
        #pragma unroll
        for (int mi = 0; mi < 2; ++mi)
            #pragma unroll
            for (int r = 0; r < 4; ++r) {
                int lrow = mi * 16 + quad * 4 + r;
                rs[wv][lrow]  = ps[mi][r];
                rs2[wv][lrow] = ps2[mi][r];
            }
    }
    __syncthreads();

    #pragma unroll
    for (int mi = 0; mi < 2; ++mi) {
        #pragma unroll
        for (int r = 0; r < 4; ++r) {
            int lrow = mi * 16 + quad * 4 + r;
            int row  = row0 + lrow;
            float tot  = rs[0][lrow] + rs[1][lrow] + rs[2][lrow] + rs[3][lrow];
            float tot2 = rs2[0][lrow] + rs2[1][lrow] + rs2[2][lrow] + rs2[3][lrow];
            float mean = tot * (1.f / (float)DM);
            float var  = tot2 * (1.f / (float)DM) - mean * mean;
            float inv  = 1.0f / sqrtf(var + 1e-5f);
            #pragma unroll
            for (int ni = 0; ni < 4; ++ni) {
                int col = wc + ni * 16 + l16;
                float val = (acc[mi][ni][r] - mean) * inv * gcol[ni] + bcol[ni];
                h[(size_t)row * DM + col]  = val;
                hb[(size_t)row * DM + col] = f2b(val);
                if (HEAD && lrow == 31) hrowS[col] = val;   // last row of block
            }
        }
    }

    if (HEAD) {
        __syncthreads();
        // blocks covering row (b*2048 + 2047): blockIdx = b*64 + 63
        if ((blockIdx.x & 63) == 63 && t < 64) {
            int b = blockIdx.x >> 6;
            float s = 0.f;
            for (int kk = 0; kk < DM; ++kk)
                s = fmaf(hrowS[kk], w1[kk * 64 + t], s);
            s += b1[t];
            s = s > 0.f ? s : 0.f;
            float contrib = s * w2[t];
            #pragma unroll
            for (int off = 32; off > 0; off >>= 1)
                contrib += __shfl_down(contrib, off, 64);
            if (t == 0) out[b] = contrib + b2[0];
        }
    }
}

// ---------------------------------------------------------------------------
// fused preproc: all weight transposes+cvt, bias pack, x cvt in ONE dispatch.
// ---------------------------------------------------------------------------
__device__ inline void tcvt_dev(float (*tile)[33], const float* __restrict__ src,
                                ushort_t* __restrict__ dst, int K, int N,
                                int matStride, int bi)
{
    int tilesN = N >> 5;
    int tpm = (K >> 5) * tilesN;
    int m   = bi / tpm;
    int tid = bi % tpm;
    int k0 = (tid / tilesN) << 5, n0 = (tid % tilesN) << 5;
    const float* s = src + (size_t)m * K * N;
    ushort_t*    d = dst + (size_t)m * matStride;
    int r = threadIdx.x >> 5, c = threadIdx.x & 31;
    #pragma unroll
    for (int i = 0; i < 4; ++i)
        tile[r + 8 * i][c] = s[(size_t)(k0 + r + 8 * i) * N + n0 + c];
    __syncthreads();
    #pragma unroll
    for (int i = 0; i < 4; ++i)
        d[(size_t)(n0 + r + 8 * i) * K + k0 + c] = f2b(tile[c][r + 8 * i]);
}

__global__ __launch_bounds__(256)
void preproc_k(const float* __restrict__ wq, const float* __restrict__ wk,
               const float* __restrict__ wv, const float* __restrict__ wo,
               const float* __restrict__ wf1, const float* __restrict__ wf2,
               const float* __restrict__ w_in,
               const float* __restrict__ bq, const float* __restrict__ bk,
               const float* __restrict__ bv, const float* __restrict__ x,
               ushort_t* __restrict__ wqkvT, ushort_t* __restrict__ woT,
               ushort_t* __restrict__ wf1T, ushort_t* __restrict__ wf2T,
               ushort_t* __restrict__ w_inT, float* __restrict__ bqkv,
               ushort_t* __restrict__ xb16)
{
    __shared__ float tile[32][33];
    int b = blockIdx.x;
    if (b < 512) {
        int which = b >> 7, lb = b & 127;
        const float* src = which == 0 ? wq : which == 1 ? wk : which == 2 ? wv : wo;
        ushort_t* dst = which == 0 ? wqkvT : which == 1 ? wqkvT + 65536
                       : which == 2 ? wqkvT + 131072 : woT;
        int stride = which == 3 ? 65536 : 768 * 256;
        tcvt_dev(tile, src, dst, DM, DM, stride, lb);
    } else if (b < 1024) {
        tcvt_dev(tile, wf1, wf1T, DM, DFF, 1024 * 256, b - 512);
    } else if (b < 1536) {
        tcvt_dev(tile, wf2, wf2T, DFF, DM, 256 * 1024, b - 1024);
    } else if (b < 1544) {
        tcvt_dev(tile, w_in, w_inT, 32, DM, 256 * 32, b - 1536);
    } else if (b < 1550) {
        int t = (b - 1544) * 256 + threadIdx.x;
        int i = t / 768, j = t % 768;
        const float* s = j < 256 ? bq : (j < 512 ? bk : bv);
        bqkv[t] = s[i * 256 + (j & 255)];
    } else {
        int tid = (b - 1550) * 256 + threadIdx.x;
        float4 v = ((const float4*)x)[tid];
        unsigned int lo = f2b(v.x) | ((unsigned int)f2b(v.y) << 16);
        unsigned int hi = f2b(v.z) | ((unsigned int)f2b(v.w) << 16);
        ((uint2*)xb16)[tid] = make_uint2(lo, hi);
    }
}

// ---------------------------------------------------------------------------
// metric v3: lane = bh, wave = one query position l. kT[l][bh][d] reads are
// fully coalesced. Also zeroes jidx for its 4 l positions. grid 512 x 256.
// ---------------------------------------------------------------------------
__global__ __launch_bounds__(256)
void metric2_k(const float* __restrict__ qb, const ushort_t* __restrict__ kT,
               const int* __restrict__ idx, float* __restrict__ Mout,
               unsigned int* __restrict__ jidx32)
{
    __shared__ float mst[64][5];
    int t = threadIdx.x;
    int w = t >> 6, lane = t & 63;
    int l = blockIdx.x * 4 + w;

    if (t < 64) {
        int zb = t >> 3, sel = t & 7;
        int zl = blockIdx.x * 4 + (sel >> 1), half = sel & 1;
        jidx32[(size_t)(zb * LL + zl) * 2 + half] = 0;
    }

    const float4* qr = (const float4*)(qb + ((size_t)(lane * LL + l) << 5));
    float4 q[8];
    #pragma unroll
    for (int i = 0; i < 8; ++i) q[i] = qr[i];

    int r40 = idx[l * SS + (lane < SS ? lane : SS - 1)];

    float mx = -3e38f, sm = 0.f;
    for (int s = 0; s < SS; ++s) {
        int r = __shfl(r40, s, 64);
        const uint4* kr = (const uint4*)(kT + (((size_t)r << 6) + lane) * 32);
        float d = 0.f;
        #pragma unroll
        for (int ww = 0; ww < 4; ++ww) {
            uint4 kv = kr[ww];
            float4 qa = q[2 * ww], qb2 = q[2 * ww + 1];
            d = fmaf(__uint_as_float(kv.x << 16),         qa.x, d);
            d = fmaf(__uint_as_float(kv.x & 0xffff0000u), qa.y, d);
            d = fmaf(__uint_as_float(kv.y << 16),         qa.z, d);
            d = fmaf(__uint_as_float(kv.y & 0xffff0000u), qa.w, d);
            d = fmaf(__uint_as_float(kv.z << 16),         qb2.x, d);
            d = fmaf(__uint_as_float(kv.z & 0xffff0000u), qb2.y, d);
            d = fmaf(__uint_as_float(kv.w << 16),         qb2.z, d);
            d = fmaf(__uint_as_float(kv.w & 0xffff0000u), qb2.w, d);
        }
        mx = fmaxf(mx, d);
        sm += d;
    }
    mst[lane][w] = mx - sm * (1.0f / (float)LL);
    __syncthreads();

    int bh = t >> 2, ls = t & 3;
    Mout[(size_t)bh * LL + blockIdx.x * 4 + ls] = mst[bh][ls];
}

// ---------------------------------------------------------------------------
// topkf: fused top-40. grid 64 x 512 threads: 8 waves/block, wave w runs the
// stage-1 slice argmax for slice w, then in-LDS rank-select.
// ---------------------------------------------------------------------------
__global__ __launch_bounds__(512)
void topkf_k(const float* __restrict__ Mout, int* __restrict__ top,
             uchar_t* __restrict__ jidx)
{
    __shared__ float cvS[320];
    __shared__ int   ciS[320];
    int bh = blockIdx.x;
    int t  = threadIdx.x;
    int lane = t & 63, w = t >> 6;   // w = slice 0..7
    int l0 = w << 8;

    float v[4];
    #pragma unroll
    for (int i = 0; i < 4; ++i)
        v[i] = Mout[(size_t)bh * LL + l0 + i * 64 + lane];

    for (int r = 0; r < UU; ++r) {
        float bv = -3e38f; int bi = 1 << 30;
        #pragma unroll
        for (int i = 0; i < 4; ++i) {
            int idx = l0 + i * 64 + lane;
            if (v[i] > bv || (v[i] == bv && idx < bi)) { bv = v[i]; bi = idx; }
        }
        #pragma unroll
        for (int off = 32; off > 0; off >>= 1) {
            float ov = __shfl_down(bv, off, 64);
            int   oi = __shfl_down(bi, off, 64);
            if (ov > bv || (ov == bv && oi < bi)) { bv = ov; bi = oi; }
        }
        bv = __shfl(bv, 0, 64);
        bi = __shfl(bi, 0, 64);
        if (lane == 0) { cvS[w * UU + r] = bv; ciS[w * UU + r] = bi; }
        int rel = bi - l0;
        if ((rel & 63) == lane) v[rel >> 6] = -3e38f;
    }
    __syncthreads();

    for (int c = t; c < 320; c += 512) {
        float mv = cvS[c]; int mi = ciS[c];
        int rank = 0;
        for (int j = 0; j < 320; ++j)
            rank += (cvS[j] > mv) || (cvS[j] == mv && ciS[j] < mi);
        if (rank < UU) {
            top[bh * UU + rank] = mi;
            int b = bh >> 3, hh = bh & 7;
            jidx[(size_t)(b * LL + mi) * 8 + hh] = (uchar_t)(rank + 1);
        }
    }
}

// ---------------------------------------------------------------------------
// attnupd v4 (MFMA): block = bh*NSL + slice (512 blocks), 256 l per slice.
// QK^T and PV via mfma_f32_16x16x32_bf16; scores fp32 in LDS (stride SCP);
// K and V share one LDS buffer (K dead after QK). Emits mP/sP/OP + vmeanP.
// ---------------------------------------------------------------------------
__global__ __launch_bounds__(256)
void attnupd_k(const float* __restrict__ qb, const float* __restrict__ kb,
               const float* __restrict__ vb, const int* __restrict__ top,
               float* __restrict__ mP, float* __restrict__ sP,
               float* __restrict__ OP, float* __restrict__ vmeanP)
{
    __shared__ ushort_t qs[48 * KP];     // 3.84 KB (rows 40..47 zero)
    __shared__ ushort_t kv[256 * KP];    // 20 KB (K with stride KP, then V with VP)
    __shared__ float    sc[48 * SCP];    // 49.9 KB
    __shared__ float    msh[UU];
    __shared__ float    red[8][32];

    int blk = blockIdx.x;
    int sl  = blk & (NSL - 1);
    int bh  = blk >> 3;
    int t   = threadIdx.x;
    int l0  = sl << 8;
    int lane = t & 63, wvx = t >> 6;
    int quad = lane >> 4, l16 = lane & 15;
    const float scale = 0.17677669529663687f;   // 1/sqrt(32)

    // stage q_top bf16 (zero-pad rows 40..47) and k slice bf16
    for (int i = t; i < 48 * 32; i += 256) {
        int j = i >> 5, dd = i & 31;
        float v = (j < UU) ? qb[((size_t)(bh * LL + top[bh * UU + j]) << 5) + dd] : 0.f;
        qs[j * KP + dd] = f2b(v);
    }
    {
        const float4* kr = (const float4*)(kb + ((size_t)(bh * LL + l0 + t) << 5));
        #pragma unroll
        for (int i = 0; i < 8; ++i) {
            float4 kx = kr[i];
            *(unsigned int*)&kv[t * KP + 4 * i] =
                (unsigned int)f2b(kx.x) | ((unsigned int)f2b(kx.y) << 16);
            *(unsigned int*)&kv[t * KP + 4 * i + 2] =
                (unsigned int)f2b(kx.z) | ((unsigned int)f2b(kx.w) << 16);
        }
    }
    __syncthreads();

    // QK^T MFMA: wave covers N-tiles (l) wvx*4..+3, M-tiles (j) 0..2
    {
        short8 afq[3];
        #pragma unroll
        for (int mt = 0; mt < 3; ++mt)
            afq[mt] = *(const short8*)&qs[(mt * 16 + l16) * KP + quad * 8];
        #pragma unroll
        for (int n4 = 0; n4 < 4; ++n4) {
            int nt = wvx * 4 + n4;
            short8 bk = *(const short8*)&kv[(nt * 16 + l16) * KP + quad * 8];
            #pragma unroll
            for (int mt = 0; mt < 3; ++mt) {
                f32x4 dd = {0.f, 0.f, 0.f, 0.f};
                dd = __builtin_amdgcn_mfma_f32_16x16x32_bf16(afq[mt], bk, dd, 0, 0, 0);
                #pragma unroll
                for (int r = 0; r < 4; ++r)
                    sc[(mt * 16 + quad * 4 + r) * SCP + nt * 16 + l16] = dd[r] * scale;
            }
        }
    }
    __syncthreads();

    // per-j max
    int j8 = t >> 5, d = t & 31;
    #pragma unroll
    for (int g = 0; g < 5; ++g) {
        int j = g * 8 + j8;
        float4 a = *(const float4*)&sc[j * SCP + 4 * d];
        float4 b = *(const float4*)&sc[j * SCP + 128 + 4 * d];
        float m = fmaxf(fmaxf(fmaxf(a.x, a.y), fmaxf(a.z, a.w)),
                        fmaxf(fmaxf(b.x, b.y), fmaxf(b.z, b.w)));
        #pragma unroll
        for (int off = 16; off > 0; off >>= 1)
            m = fmaxf(m, __shfl_down(m, off, 64));
        if (d == 0) msh[j] = m;
    }
    __syncthreads();

    // exp (vectorized)
    #pragma unroll 2
    for (int i = t; i < UU * 64; i += 256) {
        int j = i >> 6;
        float* p = &sc[j * SCP + (i & 63) * 4];
        float4 e = *(float4*)p;
        float mm = msh[j];
        e.x = __expf(e.x - mm); e.y = __expf(e.y - mm);
        e.z = __expf(e.z - mm); e.w = __expf(e.w - mm);
        *(float4*)p = e;
    }
    __syncthreads();

    int pq = bh * NSL + sl;

    // sums -> sP/mP ; stage V bf16 (stride VP, reuses kv) ; vmean partials
    #pragma unroll
    for (int g = 0; g < 5; ++g) {
        int j = g * 8 + j8;
        float4 a = *(const float4*)&sc[j * SCP + 4 * d];
        float4 b = *(const float4*)&sc[j * SCP + 128 + 4 * d];
        float s = a.x + a.y + a.z + a.w + b.x + b.y + b.z + b.w;
        #pragma unroll
        for (int off = 16; off > 0; off >>= 1)
            s += __shfl_down(s, off, 64);
        if (d == 0) { sP[pq * UU + j] = s; mP[pq * UU + j] = msh[j]; }
    }
    {
        const float4* vr = (const float4*)(vb + ((size_t)(bh * LL + l0 + t) << 5));
        #pragma unroll
        for (int i = 0; i < 8; ++i) {
            float4 vx = vr[i];
            *(unsigned int*)&kv[t * VP + 4 * i] =
                (unsigned int)f2b(vx.x) | ((unsigned int)f2b(vx.y) << 16);
            *(unsigned int*)&kv[t * VP + 4 * i + 2] =
                (unsigned int)f2b(vx.z) | ((unsigned int)f2b(vx.w) << 16);
        }
        const float* base = vb + ((size_t)(bh * LL + l0 + j8 * 32) << 5) + d;
        float s = 0.f;
        #pragma unroll 8
        for (int i = 0; i < 32; ++i) s += base[(size_t)i << 5];
        red[j8][d] = s;
    }
    __syncthreads();

    if (t < 32) {
        float tot = 0.f;
        #pragma unroll
        for (int p = 0; p < 8; ++p) tot += red[p][t];
        vmeanP[pq * 32 + t] = tot;
    }

    // PV MFMA: waves 0..2 handle M-tile wvx (j), N = 32 d (2 tiles), K = 256 l
    if (wvx < 3) {
        f32x4 acc0 = {0.f, 0.f, 0.f, 0.f};
        f32x4 acc1 = {0.f, 0.f, 0.f, 0.f};
        #pragma unroll
        for (int ks = 0; ks < 8; ++ks) {
            float4 p0 = *(const float4*)&sc[(wvx * 16 + l16) * SCP + ks * 32 + quad * 8];
            float4 p1 = *(const float4*)&sc[(wvx * 16 + l16) * SCP + ks * 32 + quad * 8 + 4];
            short8 af;
            af[0] = (short)f2b(p0.x); af[1] = (short)f2b(p0.y);
            af[2] = (short)f2b(p0.z); af[3] = (short)f2b(p0.w);
            af[4] = (short)f2b(p1.x); af[5] = (short)f2b(p1.y);
            af[6] = (short)f2b(p1.z); af[7] = (short)f2b(p1.w);
            #pragma unroll
            for (int nt = 0; nt < 2; ++nt) {
                short8 bf;
                #pragma unroll
                for (int jj = 0; jj < 8; ++jj)
                    bf[jj] = (short)kv[(ks * 32 + quad * 8 + jj) * VP + nt * 16 + l16];
                if (nt == 0)
                    acc0 = __builtin_amdgcn_mfma_f32_16x16x32_bf16(af, bf, acc0, 0, 0, 0);
                else
                    acc1 = __builtin_amdgcn_mfma_f32_16x16x32_bf16(af, bf, acc1, 0, 0, 0);
            }
        }
        #pragma unroll
        for (int r = 0; r < 4; ++r) {
            int j = wvx * 16 + quad * 4 + r;
            if (j < UU) {
                OP[((size_t)pq * UU + j) * 32 + l16]      = acc0[r];
                OP[((size_t)pq * UU + j) * 32 + 16 + l16] = acc1[r];
            }
        }
    }
}

// ---------------------------------------------------------------------------
// fillcomb: ctx bf16 = vmean broadcast (slice partials summed inline);
// scattered (top) rows get the merged softmax update via jidx.
// ---------------------------------------------------------------------------
__global__ __launch_bounds__(256)
void fillcomb_k(const float* __restrict__ vmeanP, const uchar_t* __restrict__ jidx,
                const float* __restrict__ mP, const float* __restrict__ sP,
                const float* __restrict__ OP, ushort_t* __restrict__ ctxb)
{
    int tid = blockIdx.x * 256 + threadIdx.x;   // over BL*DM/2 pairs
    int pr   = tid & 127;
    int rowi = tid >> 7;          // b*2048 + l
    int b    = rowi >> 11;
    int hh   = pr >> 4;
    int bh   = b * 8 + hh;
    int d0   = (pr * 2) & 31;
    int j    = (int)jidx[(size_t)rowi * 8 + hh];

    float v0, v1;
    if (j == 0) {
        float s0 = 0.f, s1 = 0.f;
        #pragma unroll
        for (int q = 0; q < NSL; ++q) {
            s0 += vmeanP[(bh * NSL + q) * 32 + d0];
            s1 += vmeanP[(bh * NSL + q) * 32 + d0 + 1];
        }
        v0 = s0 * (1.f / (float)LL);
        v1 = s1 * (1.f / (float)LL);
    } else {
        int jj = j - 1;
        float M = -3e38f;
        #pragma unroll
        for (int q = 0; q < NSL; ++q) M = fmaxf(M, mP[(bh * NSL + q) * UU + jj]);
        float S = 0.f, O0 = 0.f, O1 = 0.f;
        #pragma unroll
        for (int q = 0; q < NSL; ++q) {
            float wgt = __expf(mP[(bh * NSL + q) * UU + jj] - M);
            S  = fmaf(sP[(bh * NSL + q) * UU + jj], wgt, S);
            O0 = fmaf(OP[((size_t)(bh * NSL + q) * UU + jj) * 32 + d0], wgt, O0);
            O1 = fmaf(OP[((size_t)(bh * NSL + q) * UU + jj) * 32 + d0 + 1], wgt, O1);
        }
        v0 = O0 / S;
        v1 = O1 / S;
    }
    ((unsigned int*)ctxb)[tid] = (unsigned int)f2b(v0) | ((unsigned int)f2b(v1) << 16);
}

extern "C" void kernel_launch(void* const* d_in, const int* in_sizes, int n_in,
                              void* d_out, int out_size, void* d_ws, size_t ws_size,
                              hipStream_t stream)
{
    const float* x    = (const float*)d_in[0];
    const int*   idx  = (const int*)  d_in[1];
    const float* w_in = (const float*)d_in[2];
    const float* b_in = (const float*)d_in[3];
    const float* wq   = (const float*)d_in[4];
    const float* bq   = (const float*)d_in[5];
    const float* wk   = (const float*)d_in[6];
    const float* bk   = (const float*)d_in[7];
    const float* wv   = (const float*)d_in[8];
    const float* bv   = (const float*)d_in[9];
    const float* wo   = (const float*)d_in[10];
    const float* bo   = (const float*)d_in[11];
    const float* wf1  = (const float*)d_in[12];
    const float* bf1  = (const float*)d_in[13];
    const float* wf2  = (const float*)d_in[14];
    const float* bf2  = (const float*)d_in[15];
    const float* g1   = (const float*)d_in[16];
    const float* be1  = (const float*)d_in[17];
    const float* g2   = (const float*)d_in[18];
    const float* be2  = (const float*)d_in[19];
    const float* wfc1 = (const float*)d_in[20];
    const float* bfc1 = (const float*)d_in[21];
    const float* wfc2 = (const float*)d_in[22];
    const float* bfc2 = (const float*)d_in[23];
    float* out = (float*)d_out;

    float* ws = (float*)d_ws;
    float*    h     = ws;                          // [0, 4194304)
    float*    qkv   = ws + 4194304;                // [4194304, 16777216)
    float*    qb    = qkv;
    float*    kb    = qkv + 4194304;
    float*    vb    = qkv + 8388608;
    // attn scratch region (4194304 floats), all dead outside attention phase
    float*    attnS = ws + 16777216;
    ushort_t* kT16  = (ushort_t*)attnS;            //   fl [0, 2097152): kT bf16
    float*    Mbuf  = attnS + 2097152;             //   fl [2097152, 2228224)
    float*    vmeP  = attnS + 2269184;             //   16384
    float*    OP    = attnS + 2285568;             //   655360
    float*    mP    = attnS + 2940928;             //   20480
    float*    sP    = attnS + 2961408;             //   20480
    uchar_t*  jidx  = (uchar_t*)(attnS + 2981888); //   32768 fl (131072 bytes)
    // long-lived scratch — offsets in FLOATS
    float*    scr   = ws + 20971520;
    ushort_t* xb16  = (ushort_t*)scr;              //   fl [0, 262144)
    int*      top   = (int*)(scr + 264192);        //   fl [264192, 266752)
    ushort_t* hb    = (ushort_t*)(scr + 266752);   //   fl [266752, 2363904)
    ushort_t* wqkvT = (ushort_t*)(scr + 2363904);  //   fl [2363904, 2560512)
    ushort_t* woT   = (ushort_t*)(scr + 2560512);  //   fl [2560512, 2626048)
    ushort_t* wf1T  = (ushort_t*)(scr + 2626048);  //   fl [2626048, 2888192)
    ushort_t* wf2T  = (ushort_t*)(scr + 2888192);  //   fl [2888192, 3150336)
    ushort_t* w_inT = (ushort_t*)(scr + 3150336);  //   fl [3150336, 3154432)
    float*    bqkv  = scr + 3154432;               //   fl [3154432, 3155968)
    ushort_t* ctxb  = (ushort_t*)qkv;              // aliases dead q
    ushort_t* ffbb  = (ushort_t*)(qkv + 2097152);  // aliases dead q/k/v

    dim3 blk(256);

    preproc_k<<<dim3(2062), blk, 0, stream>>>(
        wq, wk, wv, wo, wf1, wf2, w_in, bq, bk, bv, x,
        wqkvT, woT, wf1T, wf2T, w_inT, bqkv, xb16);

    gemm_mfma<0,3><<<dim3(BL/128, 2), blk, 0, stream>>>(
        xb16, w_inT, b_in, (void*)h, (void*)hb, BL, DM, 32);

    for (int i = 0; i < 2; ++i) {
        gemm_mfma<0,1><<<dim3(BL/128, 6), blk, 0, stream>>>(
            hb, wqkvT + (size_t)i*768*256, bqkv + i*768, (void*)qkv, (void*)kT16,
            BL, 768, DM);

        metric2_k<<<dim3(512), blk, 0, stream>>>(
            qb, kT16, idx + (size_t)i*LL*SS, Mbuf, (unsigned int*)jidx);
        topkf_k<<<dim3(BB*NH), dim3(512), 0, stream>>>(Mbuf, top, jidx);
        attnupd_k<<<dim3(BB*NH*NSL), blk, 0, stream>>>(qb, kb, vb, top, mP, sP, OP, vmeP);
        fillcomb_k<<<dim3(BL*DM/512), blk, 0, stream>>>(vmeP, jidx, mP, sP, OP, ctxb);

        // fused O-proj + residual + LN1
        gemmln_k<0><<<dim3(BL/32), blk, 0, stream>>>(
            ctxb, woT + (size_t)i*256*256, bo + i*DM, h, hb,
            g1 + i*DM, be1 + i*DM, DM,
            nullptr, nullptr, nullptr, nullptr, nullptr);

        gemm_mfma<1,2><<<dim3(BL/128, 8), blk, 0, stream>>>(
            hb, wf1T + (size_t)i*1024*256, bf1 + i*DFF, (void*)ffbb, nullptr, BL, DFF, DM);

        // fused FF2 + residual + LN2 (+ MLP head on the last layer)
        if (i == 1) {
            gemmln_k<1><<<dim3(BL/32), blk, 0, stream>>>(
                ffbb, wf2T + (size_t)i*256*1024, bf2 + i*DM, h, hb,
                g2 + i*DM, be2 + i*DM, DFF,
                wfc1, bfc1, wfc2, bfc2, out);
        } else {
            gemmln_k<0><<<dim3(BL/32), blk, 0, stream>>>(
                ffbb, wf2T + (size_t)i*256*1024, bf2 + i*DM, h, hb,
                g2 + i*DM, be2 + i*DM, DFF,
                nullptr, nullptr, nullptr, nullptr, nullptr);
        }
    }
}

// Round 14
// 462.776 us; speedup vs baseline: 1.2182x; 1.0244x over previous
//
#include <hip/hip_runtime.h>
#include <math.h>

#define BB 8
#define LL 2048
#define DM 256
#define NH 8
#define DH 32
#define DFF 1024
#define SS 40
#define UU 40
#define BL (BB*LL)   // 16384
#define NSL 8        // attnupd L-slices per (b,h)

// attnupd LDS layout constants
#define SCP 260      // sc row stride (floats) — breaks 16-way bank aliasing
#define KP  40       // k/q row stride (ushorts) — 16B-aligned rows for b128
#define VP  34       // v row stride (ushorts) — ~2-way for column u16 gathers

typedef unsigned short ushort_t;
typedef unsigned char uchar_t;
typedef __attribute__((ext_vector_type(8))) short short8;
typedef __attribute__((ext_vector_type(4))) float f32x4;

__device__ inline ushort_t f2b(float f)
{
    unsigned int u = __float_as_uint(f);
    u += 0x7fff + ((u >> 16) & 1);      // round-to-nearest-even
    return (ushort_t)(u >> 16);
}

__device__ inline float blo(unsigned int u) { return __uint_as_float(u << 16); }
__device__ inline float bhi(unsigned int u) { return __uint_as_float(u & 0xffff0000u); }

__device__ inline void gload16(const void* g, const void* l)
{
    __builtin_amdgcn_global_load_lds(
        (const __attribute__((address_space(1))) unsigned int*)g,
        (__attribute__((address_space(3))) unsigned int*)l, 16, 0, 0);
}

// ---------------------------------------------------------------------------
// bf16 MFMA GEMM, m97 structure. 128x128 tile, BK=32, 256 thr.
// OUT_MODE: 0 fp32 RM | 1 QKV scatter (bf16 q,k,v BHLD + bf16 kT[l][bh][d])
//           2 bf16 RM | 3 fp32 RM + bf16 RM into aux
// ---------------------------------------------------------------------------
template<int RELU, int OUT_MODE>
__global__ __launch_bounds__(256)
void gemm_mfma(const ushort_t* __restrict__ A, const ushort_t* __restrict__ Bt,
               const float* __restrict__ bias, void* __restrict__ Cout,
               void* __restrict__ aux, int M, int N, int K)
{
    __shared__ ushort_t Asl[128 * 32];
    __shared__ ushort_t Bsl[128 * 32];

    const int t    = threadIdx.x;
    const int lane = t & 63;
    const int wv   = t >> 6;
    const int row0 = blockIdx.x * 128;
    const int col0 = blockIdx.y * 128;
    const int wr   = (wv >> 1) * 64;
    const int wc   = (wv & 1) * 64;
    const int quad = lane >> 4;
    const int l16  = lane & 15;

    f32x4 acc[4][4];
    #pragma unroll
    for (int i = 0; i < 4; ++i)
        #pragma unroll
        for (int j = 0; j < 4; ++j)
            acc[i][j] = 0.f;

    for (int k0 = 0; k0 < K; k0 += 32) {
        __syncthreads();
        #pragma unroll
        for (int r = 0; r < 2; ++r) {
            int g = r * 256 + t;
            const ushort_t* ga = A  + (size_t)(row0 + (g >> 2)) * K + k0 + (g & 3) * 8;
            const ushort_t* gb = Bt + (size_t)(col0 + (g >> 2)) * K + k0 + (g & 3) * 8;
            int lbase = (r * 256 + wv * 64) * 16;
            gload16(ga, (const char*)Asl + lbase);
            gload16(gb, (const char*)Bsl + lbase);
        }
        __syncthreads();

        short8 af[4], bfr[4];
        #pragma unroll
        for (int mi = 0; mi < 4; ++mi)
            af[mi] = *(const short8*)&Asl[(wr + mi * 16 + l16) * 32 + quad * 8];
        #pragma unroll
        for (int ni = 0; ni < 4; ++ni)
            bfr[ni] = *(const short8*)&Bsl[(wc + ni * 16 + l16) * 32 + quad * 8];
        #pragma unroll
        for (int mi = 0; mi < 4; ++mi)
            #pragma unroll
            for (int ni = 0; ni < 4; ++ni)
                acc[mi][ni] = __builtin_amdgcn_mfma_f32_16x16x32_bf16(
                    af[mi], bfr[ni], acc[mi][ni], 0, 0, 0);
    }

    #pragma unroll
    for (int mi = 0; mi < 4; ++mi) {
        #pragma unroll
        for (int ni = 0; ni < 4; ++ni) {
            int col = col0 + wc + ni * 16 + l16;
            float bb = bias[col];
            #pragma unroll
            for (int r = 0; r < 4; ++r) {
                int row = row0 + wr + mi * 16 + quad * 4 + r;
                float v = acc[mi][ni][r] + bb;
                if (RELU) v = v > 0.f ? v : 0.f;
                if (OUT_MODE == 0) {
                    ((float*)Cout)[(size_t)row * N + col] = v;
                } else if (OUT_MODE == 1) {
                    int tensor = col >> 8;          // 0=q 1=k 2=v
                    int c2 = col & 255;
                    int b  = row >> 11, l = row & (LL - 1);
                    int hh = c2 >> 5,  dh = c2 & 31;
                    int bh = b * NH + hh;
                    size_t bi = (((size_t)bh * LL + l) << 5) + dh;
                    ushort_t vb16 = f2b(v);
                    ((ushort_t*)Cout)[(size_t)tensor * (BB*NH*LL*DH) + bi] = vb16;
                    if (tensor == 1)   // kT[l][bh][d] bf16 for metric
                        ((ushort_t*)aux)[(((size_t)l << 6) + bh) * 32 + dh] = vb16;
                } else if (OUT_MODE == 2) {
                    ((ushort_t*)Cout)[(size_t)row * N + col] = f2b(v);
                } else {
                    ((float*)Cout)[(size_t)row * N + col] = v;
                    ((ushort_t*)aux)[(size_t)row * N + col] = f2b(v);
                }
            }
        }
    }
}

// ---------------------------------------------------------------------------
// Fused GEMM (Mx256, K param) + residual + LayerNorm (+ optional MLP head):
//   h = LN(h + A@Bt^T + bias) * g + beta ; writes h fp32 + hb bf16.
// 32x256 tile, grid M/32 = 512 blocks (2/CU), 4 waves (wave = 64 cols).
// ---------------------------------------------------------------------------
template<int HEAD>
__global__ __launch_bounds__(256)
void gemmln_k(const ushort_t* __restrict__ A, const ushort_t* __restrict__ Bt,
              const float* __restrict__ bias, float* __restrict__ h,
              ushort_t* __restrict__ hb, const float* __restrict__ g,
              const float* __restrict__ beta, int K,
              const float* __restrict__ w1, const float* __restrict__ b1,
              const float* __restrict__ w2, const float* __restrict__ b2,
              float* __restrict__ out)
{
    __shared__ ushort_t Asl[32 * 32];    // 2 KB
    __shared__ ushort_t Bsl[256 * 32];   // 16 KB
    __shared__ float rs[4][32], rs2[4][32];
    __shared__ float hrowS[256];

    const int t    = threadIdx.x;
    const int lane = t & 63;
    const int wv   = t >> 6;
    const int row0 = blockIdx.x * 32;
    const int wc   = wv * 64;
    const int quad = lane >> 4;
    const int l16  = lane & 15;

    f32x4 acc[2][4];
    #pragma unroll
    for (int i = 0; i < 2; ++i)
        #pragma unroll
        for (int j = 0; j < 4; ++j)
            acc[i][j] = 0.f;

    for (int k0 = 0; k0 < K; k0 += 32) {
        __syncthreads();
        if (wv < 2) {   // A tile: 32 rows x 32 k = 2 KB, waves 0-1
            const ushort_t* ga = A + (size_t)(row0 + (t >> 2)) * K + k0 + (t & 3) * 8;
            gload16(ga, (const char*)Asl + wv * 1024);
        }
        #pragma unroll
        for (int r = 0; r < 4; ++r) {   // B tile: 256 rows x 32 k = 16 KB
            int gg = r * 256 + t;
            const ushort_t* gb = Bt + (size_t)(gg >> 2) * K + k0 + (gg & 3) * 8;
            gload16(gb, (const char*)Bsl + (r * 256 + wv * 64) * 16);
        }
        __syncthreads();

        short8 af[2], bfr[4];
        #pragma unroll
        for (int mi = 0; mi < 2; ++mi)
            af[mi] = *(const short8*)&Asl[(mi * 16 + l16) * 32 + quad * 8];
        #pragma unroll
        for (int ni = 0; ni < 4; ++ni)
            bfr[ni] = *(const short8*)&Bsl[(wc + ni * 16 + l16) * 32 + quad * 8];
        #pragma unroll
        for (int mi = 0; mi < 2; ++mi)
            #pragma unroll
            for (int ni = 0; ni < 4; ++ni)
                acc[mi][ni] = __builtin_amdgcn_mfma_f32_16x16x32_bf16(
                    af[mi], bfr[ni], acc[mi][ni], 0, 0, 0);
    }

    float gcol[4], bcol[4];
    #pragma unroll
    for (int ni = 0; ni < 4; ++ni) {
        int col = wc + ni * 16 + l16;
        gcol[ni] = g[col];
        bcol[ni] = beta[col];
    }
    float ps[2][4], ps2[2][4];
    #pragma unroll
    for (int mi = 0; mi < 2; ++mi) {
        #pragma unroll
        for (int r = 0; r < 4; ++r) {
            int row = row0 + mi * 16 + quad * 4 + r;
            float s = 0.f, s2 = 0.f;
            #pragma unroll
            for (int ni = 0; ni < 4; ++ni) {
                int col = wc + ni * 16 + l16;
                float v = acc[mi][ni][r] + bias[col] + h[(size_t)row * DM + col];
                acc[mi][ni][r] = v;
                s += v;
                s2 += v * v;
            }
            ps[mi][r] = s;
            ps2[mi][r] = s2;
        }
    }
    #pragma unroll
    for (int off = 1; off < 16; off <<= 1) {
        #pragma unroll
        for (int mi = 0; mi < 2; ++mi)
            #pragma unroll
            for (int r = 0; r < 4; ++r) {
                ps[mi][r]  += __shfl_xor(ps[mi][r],  off, 16);
                ps2[mi][r] += __shfl_xor(ps2[mi][r], off, 16);
            }
    }
    if (l16 == 0) {
        #pragma unroll
        for (int mi = 0; mi < 2; ++mi)
            #pragma unroll
            for (int r = 0; r < 4; ++r) {
                int lrow = mi * 16 + quad * 4 + r;
                rs[wv][lrow]  = ps[mi][r];
                rs2[wv][lrow] = ps2[mi][r];
            }
    }
    __syncthreads();

    #pragma unroll
    for (int mi = 0; mi < 2; ++mi) {
        #pragma unroll
        for (int r = 0; r < 4; ++r) {
            int lrow = mi * 16 + quad * 4 + r;
            int row  = row0 + lrow;
            float tot  = rs[0][lrow] + rs[1][lrow] + rs[2][lrow] + rs[3][lrow];
            float tot2 = rs2[0][lrow] + rs2[1][lrow] + rs2[2][lrow] + rs2[3][lrow];
            float mean = tot * (1.f / (float)DM);
            float var  = tot2 * (1.f / (float)DM) - mean * mean;
            float inv  = 1.0f / sqrtf(var + 1e-5f);
            #pragma unroll
            for (int ni = 0; ni < 4; ++ni) {
                int col = wc + ni * 16 + l16;
                float val = (acc[mi][ni][r] - mean) * inv * gcol[ni] + bcol[ni];
                h[(size_t)row * DM + col]  = val;
                hb[(size_t)row * DM + col] = f2b(val);
                if (HEAD && lrow == 31) hrowS[col] = val;   // last row of block
            }
        }
    }

    if (HEAD) {
        __syncthreads();
        if ((blockIdx.x & 63) == 63 && t < 64) {
            int b = blockIdx.x >> 6;
            float s = 0.f;
            for (int kk = 0; kk < DM; ++kk)
                s = fmaf(hrowS[kk], w1[kk * 64 + t], s);
            s += b1[t];
            s = s > 0.f ? s : 0.f;
            float contrib = s * w2[t];
            #pragma unroll
            for (int off = 32; off > 0; off >>= 1)
                contrib += __shfl_down(contrib, off, 64);
            if (t == 0) out[b] = contrib + b2[0];
        }
    }
}

// ---------------------------------------------------------------------------
// fused preproc: all weight transposes+cvt, bias pack, x cvt in ONE dispatch.
// ---------------------------------------------------------------------------
__device__ inline void tcvt_dev(float (*tile)[33], const float* __restrict__ src,
                                ushort_t* __restrict__ dst, int K, int N,
                                int matStride, int bi)
{
    int tilesN = N >> 5;
    int tpm = (K >> 5) * tilesN;
    int m   = bi / tpm;
    int tid = bi % tpm;
    int k0 = (tid / tilesN) << 5, n0 = (tid % tilesN) << 5;
    const float* s = src + (size_t)m * K * N;
    ushort_t*    d = dst + (size_t)m * matStride;
    int r = threadIdx.x >> 5, c = threadIdx.x & 31;
    #pragma unroll
    for (int i = 0; i < 4; ++i)
        tile[r + 8 * i][c] = s[(size_t)(k0 + r + 8 * i) * N + n0 + c];
    __syncthreads();
    #pragma unroll
    for (int i = 0; i < 4; ++i)
        d[(size_t)(n0 + r + 8 * i) * K + k0 + c] = f2b(tile[c][r + 8 * i]);
}

__global__ __launch_bounds__(256)
void preproc_k(const float* __restrict__ wq, const float* __restrict__ wk,
               const float* __restrict__ wv, const float* __restrict__ wo,
               const float* __restrict__ wf1, const float* __restrict__ wf2,
               const float* __restrict__ w_in,
               const float* __restrict__ bq, const float* __restrict__ bk,
               const float* __restrict__ bv, const float* __restrict__ x,
               ushort_t* __restrict__ wqkvT, ushort_t* __restrict__ woT,
               ushort_t* __restrict__ wf1T, ushort_t* __restrict__ wf2T,
               ushort_t* __restrict__ w_inT, float* __restrict__ bqkv,
               ushort_t* __restrict__ xb16)
{
    __shared__ float tile[32][33];
    int b = blockIdx.x;
    if (b < 512) {
        int which = b >> 7, lb = b & 127;
        const float* src = which == 0 ? wq : which == 1 ? wk : which == 2 ? wv : wo;
        ushort_t* dst = which == 0 ? wqkvT : which == 1 ? wqkvT + 65536
                       : which == 2 ? wqkvT + 131072 : woT;
        int stride = which == 3 ? 65536 : 768 * 256;
        tcvt_dev(tile, src, dst, DM, DM, stride, lb);
    } else if (b < 1024) {
        tcvt_dev(tile, wf1, wf1T, DM, DFF, 1024 * 256, b - 512);
    } else if (b < 1536) {
        tcvt_dev(tile, wf2, wf2T, DFF, DM, 256 * 1024, b - 1024);
    } else if (b < 1544) {
        tcvt_dev(tile, w_in, w_inT, 32, DM, 256 * 32, b - 1536);
    } else if (b < 1550) {
        int t = (b - 1544) * 256 + threadIdx.x;
        int i = t / 768, j = t % 768;
        const float* s = j < 256 ? bq : (j < 512 ? bk : bv);
        bqkv[t] = s[i * 256 + (j & 255)];
    } else {
        int tid = (b - 1550) * 256 + threadIdx.x;
        float4 v = ((const float4*)x)[tid];
        unsigned int lo = f2b(v.x) | ((unsigned int)f2b(v.y) << 16);
        unsigned int hi = f2b(v.z) | ((unsigned int)f2b(v.w) << 16);
        ((uint2*)xb16)[tid] = make_uint2(lo, hi);
    }
}

// ---------------------------------------------------------------------------
// metric v4: lane = bh, wave = one query position l. bf16 q (BHLD) + bf16
// kT[l][bh][d], both coalesced/amortized. Zeroes jidx. grid 512 x 256.
// ---------------------------------------------------------------------------
__global__ __launch_bounds__(256)
void metric2_k(const ushort_t* __restrict__ qb16, const ushort_t* __restrict__ kT,
               const int* __restrict__ idx, float* __restrict__ Mout,
               unsigned int* __restrict__ jidx32)
{
    __shared__ float mst[64][5];
    int t = threadIdx.x;
    int w = t >> 6, lane = t & 63;
    int l = blockIdx.x * 4 + w;

    if (t < 64) {
        int zb = t >> 3, sel = t & 7;
        int zl = blockIdx.x * 4 + (sel >> 1), half = sel & 1;
        jidx32[(size_t)(zb * LL + zl) * 2 + half] = 0;
    }

    float4 q[8];
    {
        const uint4* qr4 = (const uint4*)(qb16 + ((size_t)(lane * LL + l) << 5));
        #pragma unroll
        for (int i = 0; i < 4; ++i) {
            uint4 u = qr4[i];
            q[2 * i]     = make_float4(blo(u.x), bhi(u.x), blo(u.y), bhi(u.y));
            q[2 * i + 1] = make_float4(blo(u.z), bhi(u.z), blo(u.w), bhi(u.w));
        }
    }

    int r40 = idx[l * SS + (lane < SS ? lane : SS - 1)];

    float mx = -3e38f, sm = 0.f;
    for (int s = 0; s < SS; ++s) {
        int r = __shfl(r40, s, 64);
        const uint4* kr = (const uint4*)(kT + (((size_t)r << 6) + lane) * 32);
        float d = 0.f;
        #pragma unroll
        for (int ww = 0; ww < 4; ++ww) {
            uint4 kv = kr[ww];
            float4 qa = q[2 * ww], qb2 = q[2 * ww + 1];
            d = fmaf(blo(kv.x), qa.x, d);
            d = fmaf(bhi(kv.x), qa.y, d);
            d = fmaf(blo(kv.y), qa.z, d);
            d = fmaf(bhi(kv.y), qa.w, d);
            d = fmaf(blo(kv.z), qb2.x, d);
            d = fmaf(bhi(kv.z), qb2.y, d);
            d = fmaf(blo(kv.w), qb2.z, d);
            d = fmaf(bhi(kv.w), qb2.w, d);
        }
        mx = fmaxf(mx, d);
        sm += d;
    }
    mst[lane][w] = mx - sm * (1.0f / (float)LL);
    __syncthreads();

    int bh = t >> 2, ls = t & 3;
    Mout[(size_t)bh * LL + blockIdx.x * 4 + ls] = mst[bh][ls];
}

// ---------------------------------------------------------------------------
// topkf: fused top-40. grid 64 x 512 threads: 8 waves/block, wave w runs the
// stage-1 slice argmax for slice w, then in-LDS rank-select.
// ---------------------------------------------------------------------------
__global__ __launch_bounds__(512)
void topkf_k(const float* __restrict__ Mout, int* __restrict__ top,
             uchar_t* __restrict__ jidx)
{
    __shared__ float cvS[320];
    __shared__ int   ciS[320];
    int bh = blockIdx.x;
    int t  = threadIdx.x;
    int lane = t & 63, w = t >> 6;   // w = slice 0..7
    int l0 = w << 8;

    float v[4];
    #pragma unroll
    for (int i = 0; i < 4; ++i)
        v[i] = Mout[(size_t)bh * LL + l0 + i * 64 + lane];

    for (int r = 0; r < UU; ++r) {
        float bv = -3e38f; int bi = 1 << 30;
        #pragma unroll
        for (int i = 0; i < 4; ++i) {
            int idx = l0 + i * 64 + lane;
            if (v[i] > bv || (v[i] == bv && idx < bi)) { bv = v[i]; bi = idx; }
        }
        #pragma unroll
        for (int off = 32; off > 0; off >>= 1) {
            float ov = __shfl_down(bv, off, 64);
            int   oi = __shfl_down(bi, off, 64);
            if (ov > bv || (ov == bv && oi < bi)) { bv = ov; bi = oi; }
        }
        bv = __shfl(bv, 0, 64);
        bi = __shfl(bi, 0, 64);
        if (lane == 0) { cvS[w * UU + r] = bv; ciS[w * UU + r] = bi; }
        int rel = bi - l0;
        if ((rel & 63) == lane) v[rel >> 6] = -3e38f;
    }
    __syncthreads();

    for (int c = t; c < 320; c += 512) {
        float mv = cvS[c]; int mi = ciS[c];
        int rank = 0;
        for (int j = 0; j < 320; ++j)
            rank += (cvS[j] > mv) || (cvS[j] == mv && ciS[j] < mi);
        if (rank < UU) {
            top[bh * UU + rank] = mi;
            int b = bh >> 3, hh = bh & 7;
            jidx[(size_t)(b * LL + mi) * 8 + hh] = (uchar_t)(rank + 1);
        }
    }
}

// ---------------------------------------------------------------------------
// attnupd v5 (MFMA, bf16 inputs): block = bh*NSL + slice (512 blocks).
// QK^T and PV via mfma_f32_16x16x32_bf16; scores fp32 in LDS (stride SCP);
// K and V share one LDS buffer. Emits mP/sP/OP + vmeanP.
// ---------------------------------------------------------------------------
__global__ __launch_bounds__(256)
void attnupd_k(const ushort_t* __restrict__ qb16, const ushort_t* __restrict__ kb16,
               const ushort_t* __restrict__ vb16, const int* __restrict__ top,
               float* __restrict__ mP, float* __restrict__ sP,
               float* __restrict__ OP, float* __restrict__ vmeanP)
{
    __shared__ ushort_t qs[48 * KP];     // 3.84 KB (rows 40..47 zero)
    __shared__ ushort_t kv[256 * KP];    // 20 KB (K with stride KP, then V with VP)
    __shared__ float    sc[48 * SCP];    // 49.9 KB
    __shared__ float    msh[UU];
    __shared__ float    red[8][32];

    int blk = blockIdx.x;
    int sl  = blk & (NSL - 1);
    int bh  = blk >> 3;
    int t   = threadIdx.x;
    int l0  = sl << 8;
    int lane = t & 63, wvx = t >> 6;
    int quad = lane >> 4, l16 = lane & 15;
    const float scale = 0.17677669529663687f;   // 1/sqrt(32)

    // stage q_top bf16 (zero-pad rows 40..47) and k slice bf16 (plain copies)
    for (int i = t; i < 48 * 32; i += 256) {
        int j = i >> 5, dd = i & 31;
        qs[(i >> 5) * KP + dd] = (j < UU)
            ? qb16[((size_t)(bh * LL + top[bh * UU + j]) << 5) + dd] : (ushort_t)0;
    }
    {
        const unsigned int* krow =
            (const unsigned int*)(kb16 + ((size_t)(bh * LL + l0 + t) << 5));
        #pragma unroll
        for (int i = 0; i < 16; ++i)
            ((unsigned int*)kv)[t * (KP / 2) + i] = krow[i];
    }
    __syncthreads();

    // QK^T MFMA: wave covers N-tiles (l) wvx*4..+3, M-tiles (j) 0..2
    {
        short8 afq[3];
        #pragma unroll
        for (int mt = 0; mt < 3; ++mt)
            afq[mt] = *(const short8*)&qs[(mt * 16 + l16) * KP + quad * 8];
        #pragma unroll
        for (int n4 = 0; n4 < 4; ++n4) {
            int nt = wvx * 4 + n4;
            short8 bk = *(const short8*)&kv[(nt * 16 + l16) * KP + quad * 8];
            #pragma unroll
            for (int mt = 0; mt < 3; ++mt) {
                f32x4 dd = {0.f, 0.f, 0.f, 0.f};
                dd = __builtin_amdgcn_mfma_f32_16x16x32_bf16(afq[mt], bk, dd, 0, 0, 0);
                #pragma unroll
                for (int r = 0; r < 4; ++r)
                    sc[(mt * 16 + quad * 4 + r) * SCP + nt * 16 + l16] = dd[r] * scale;
            }
        }
    }
    __syncthreads();

    // per-j max
    int j8 = t >> 5, d = t & 31;
    #pragma unroll
    for (int g = 0; g < 5; ++g) {
        int j = g * 8 + j8;
        float4 a = *(const float4*)&sc[j * SCP + 4 * d];
        float4 b = *(const float4*)&sc[j * SCP + 128 + 4 * d];
        float m = fmaxf(fmaxf(fmaxf(a.x, a.y), fmaxf(a.z, a.w)),
                        fmaxf(fmaxf(b.x, b.y), fmaxf(b.z, b.w)));
        #pragma unroll
        for (int off = 16; off > 0; off >>= 1)
            m = fmaxf(m, __shfl_down(m, off, 64));
        if (d == 0) msh[j] = m;
    }
    __syncthreads();

    // exp (vectorized)
    #pragma unroll 2
    for (int i = t; i < UU * 64; i += 256) {
        int j = i >> 6;
        float* p = &sc[j * SCP + (i & 63) * 4];
        float4 e = *(float4*)p;
        float mm = msh[j];
        e.x = __expf(e.x - mm); e.y = __expf(e.y - mm);
        e.z = __expf(e.z - mm); e.w = __expf(e.w - mm);
        *(float4*)p = e;
    }
    __syncthreads();

    int pq = bh * NSL + sl;

    // sums -> sP/mP ; stage V bf16 (stride VP, reuses kv) ; vmean partials
    #pragma unroll
    for (int g = 0; g < 5; ++g) {
        int j = g * 8 + j8;
        float4 a = *(const float4*)&sc[j * SCP + 4 * d];
        float4 b = *(const float4*)&sc[j * SCP + 128 + 4 * d];
        float s = a.x + a.y + a.z + a.w + b.x + b.y + b.z + b.w;
        #pragma unroll
        for (int off = 16; off > 0; off >>= 1)
            s += __shfl_down(s, off, 64);
        if (d == 0) { sP[pq * UU + j] = s; mP[pq * UU + j] = msh[j]; }
    }
    {
        const unsigned int* vrow =
            (const unsigned int*)(vb16 + ((size_t)(bh * LL + l0 + t) << 5));
        #pragma unroll
        for (int i = 0; i < 16; ++i)
            *(unsigned int*)&kv[t * VP + 2 * i] = vrow[i];
        const ushort_t* base = vb16 + ((size_t)(bh * LL + l0 + j8 * 32) << 5) + d;
        float s = 0.f;
        #pragma unroll 8
        for (int i = 0; i < 32; ++i)
            s += __uint_as_float((unsigned int)base[(size_t)i << 5] << 16);
        red[j8][d] = s;
    }
    __syncthreads();

    if (t < 32) {
        float tot = 0.f;
        #pragma unroll
        for (int p = 0; p < 8; ++p) tot += red[p][t];
        vmeanP[pq * 32 + t] = tot;
    }

    // PV MFMA: waves 0..2 handle M-tile wvx (j), N = 32 d (2 tiles), K = 256 l
    if (wvx < 3) {
        f32x4 acc0 = {0.f, 0.f, 0.f, 0.f};
        f32x4 acc1 = {0.f, 0.f, 0.f, 0.f};
        #pragma unroll
        for (int ks = 0; ks < 8; ++ks) {
            float4 p0 = *(const float4*)&sc[(wvx * 16 + l16) * SCP + ks * 32 + quad * 8];
            float4 p1 = *(const float4*)&sc[(wvx * 16 + l16) * SCP + ks * 32 + quad * 8 + 4];
            short8 af;
            af[0] = (short)f2b(p0.x); af[1] = (short)f2b(p0.y);
            af[2] = (short)f2b(p0.z); af[3] = (short)f2b(p0.w);
            af[4] = (short)f2b(p1.x); af[5] = (short)f2b(p1.y);
            af[6] = (short)f2b(p1.z); af[7] = (short)f2b(p1.w);
            #pragma unroll
            for (int nt = 0; nt < 2; ++nt) {
                short8 bf;
                #pragma unroll
                for (int jj = 0; jj < 8; ++jj)
                    bf[jj] = (short)kv[(ks * 32 + quad * 8 + jj) * VP + nt * 16 + l16];
                if (nt == 0)
                    acc0 = __builtin_amdgcn_mfma_f32_16x16x32_bf16(af, bf, acc0, 0, 0, 0);
                else
                    acc1 = __builtin_amdgcn_mfma_f32_16x16x32_bf16(af, bf, acc1, 0, 0, 0);
            }
        }
        #pragma unroll
        for (int r = 0; r < 4; ++r) {
            int j = wvx * 16 + quad * 4 + r;
            if (j < UU) {
                OP[((size_t)pq * UU + j) * 32 + l16]      = acc0[r];
                OP[((size_t)pq * UU + j) * 32 + 16 + l16] = acc1[r];
            }
        }
    }
}

// ---------------------------------------------------------------------------
// fillcomb: ctx bf16 = vmean broadcast (slice partials summed inline);
// scattered (top) rows get the merged softmax update via jidx.
// ---------------------------------------------------------------------------
__global__ __launch_bounds__(256)
void fillcomb_k(const float* __restrict__ vmeanP, const uchar_t* __restrict__ jidx,
                const float* __restrict__ mP, const float* __restrict__ sP,
                const float* __restrict__ OP, ushort_t* __restrict__ ctxb)
{
    int tid = blockIdx.x * 256 + threadIdx.x;   // over BL*DM/2 pairs
    int pr   = tid & 127;
    int rowi = tid >> 7;          // b*2048 + l
    int b    = rowi >> 11;
    int hh   = pr >> 4;
    int bh   = b * 8 + hh;
    int d0   = (pr * 2) & 31;
    int j    = (int)jidx[(size_t)rowi * 8 + hh];

    float v0, v1;
    if (j == 0) {
        float s0 = 0.f, s1 = 0.f;
        #pragma unroll
        for (int q = 0; q < NSL; ++q) {
            s0 += vmeanP[(bh * NSL + q) * 32 + d0];
            s1 += vmeanP[(bh * NSL + q) * 32 + d0 + 1];
        }
        v0 = s0 * (1.f / (float)LL);
        v1 = s1 * (1.f / (float)LL);
    } else {
        int jj = j - 1;
        float M = -3e38f;
        #pragma unroll
        for (int q = 0; q < NSL; ++q) M = fmaxf(M, mP[(bh * NSL + q) * UU + jj]);
        float S = 0.f, O0 = 0.f, O1 = 0.f;
        #pragma unroll
        for (int q = 0; q < NSL; ++q) {
            float wgt = __expf(mP[(bh * NSL + q) * UU + jj] - M);
            S  = fmaf(sP[(bh * NSL + q) * UU + jj], wgt, S);
            O0 = fmaf(OP[((size_t)(bh * NSL + q) * UU + jj) * 32 + d0], wgt, O0);
            O1 = fmaf(OP[((size_t)(bh * NSL + q) * UU + jj) * 32 + d0 + 1], wgt, O1);
        }
        v0 = O0 / S;
        v1 = O1 / S;
    }
    ((unsigned int*)ctxb)[tid] = (unsigned int)f2b(v0) | ((unsigned int)f2b(v1) << 16);
}

extern "C" void kernel_launch(void* const* d_in, const int* in_sizes, int n_in,
                              void* d_out, int out_size, void* d_ws, size_t ws_size,
                              hipStream_t stream)
{
    const float* x    = (const float*)d_in[0];
    const int*   idx  = (const int*)  d_in[1];
    const float* w_in = (const float*)d_in[2];
    const float* b_in = (const float*)d_in[3];
    const float* wq   = (const float*)d_in[4];
    const float* bq   = (const float*)d_in[5];
    const float* wk   = (const float*)d_in[6];
    const float* bk   = (const float*)d_in[7];
    const float* wv   = (const float*)d_in[8];
    const float* bv   = (const float*)d_in[9];
    const float* wo   = (const float*)d_in[10];
    const float* bo   = (const float*)d_in[11];
    const float* wf1  = (const float*)d_in[12];
    const float* bf1  = (const float*)d_in[13];
    const float* wf2  = (const float*)d_in[14];
    const float* bf2  = (const float*)d_in[15];
    const float* g1   = (const float*)d_in[16];
    const float* be1  = (const float*)d_in[17];
    const float* g2   = (const float*)d_in[18];
    const float* be2  = (const float*)d_in[19];
    const float* wfc1 = (const float*)d_in[20];
    const float* bfc1 = (const float*)d_in[21];
    const float* wfc2 = (const float*)d_in[22];
    const float* bfc2 = (const float*)d_in[23];
    float* out = (float*)d_out;

    float* ws = (float*)d_ws;
    float*    h     = ws;                          // fl [0, 4194304)
    // bf16 q/k/v (BHLD), 4,194,304 ushorts each, in [4194304, 10485760) fl
    ushort_t* q16   = (ushort_t*)(ws + 4194304);
    ushort_t* k16   = q16 + 4194304;
    ushort_t* v16   = q16 + 8388608;
    ushort_t* ctxb  = q16;                         // aliases dead q16
    ushort_t* ffbb  = (ushort_t*)(ws + 6291456);   // aliases dead k16/v16 (+beyond)
    // attn scratch region (4194304 floats), dead outside attention phase
    float*    attnS = ws + 16777216;
    ushort_t* kT16  = (ushort_t*)attnS;            //   fl [0, 2097152): kT bf16
    float*    Mbuf  = attnS + 2097152;             //   fl [2097152, 2228224)
    float*    vmeP  = attnS + 2269184;             //   16384
    float*    OP    = attnS + 2285568;             //   655360
    float*    mP    = attnS + 2940928;             //   20480
    float*    sP    = attnS + 2961408;             //   20480
    uchar_t*  jidx  = (uchar_t*)(attnS + 2981888); //   32768 fl (131072 bytes)
    // long-lived scratch — offsets in FLOATS
    float*    scr   = ws + 20971520;
    ushort_t* xb16  = (ushort_t*)scr;              //   fl [0, 262144)
    int*      top   = (int*)(scr + 264192);        //   fl [264192, 266752)
    ushort_t* hb    = (ushort_t*)(scr + 266752);   //   fl [266752, 2363904)
    ushort_t* wqkvT = (ushort_t*)(scr + 2363904);  //   fl [2363904, 2560512)
    ushort_t* woT   = (ushort_t*)(scr + 2560512);  //   fl [2560512, 2626048)
    ushort_t* wf1T  = (ushort_t*)(scr + 2626048);  //   fl [2626048, 2888192)
    ushort_t* wf2T  = (ushort_t*)(scr + 2888192);  //   fl [2888192, 3150336)
    ushort_t* w_inT = (ushort_t*)(scr + 3150336);  //   fl [3150336, 3154432)
    float*    bqkv  = scr + 3154432;               //   fl [3154432, 3155968)

    dim3 blk(256);

    preproc_k<<<dim3(2062), blk, 0, stream>>>(
        wq, wk, wv, wo, wf1, wf2, w_in, bq, bk, bv, x,
        wqkvT, woT, wf1T, wf2T, w_inT, bqkv, xb16);

    gemm_mfma<0,3><<<dim3(BL/128, 2), blk, 0, stream>>>(
        xb16, w_inT, b_in, (void*)h, (void*)hb, BL, DM, 32);

    for (int i = 0; i < 2; ++i) {
        gemm_mfma<0,1><<<dim3(BL/128, 6), blk, 0, stream>>>(
            hb, wqkvT + (size_t)i*768*256, bqkv + i*768, (void*)q16, (void*)kT16,
            BL, 768, DM);

        metric2_k<<<dim3(512), blk, 0, stream>>>(
            q16, kT16, idx + (size_t)i*LL*SS, Mbuf, (unsigned int*)jidx);
        topkf_k<<<dim3(BB*NH), dim3(512), 0, stream>>>(Mbuf, top, jidx);
        attnupd_k<<<dim3(BB*NH*NSL), blk, 0, stream>>>(q16, k16, v16, top, mP, sP, OP, vmeP);
        fillcomb_k<<<dim3(BL*DM/512), blk, 0, stream>>>(vmeP, jidx, mP, sP, OP, ctxb);

        // fused O-proj + residual + LN1
        gemmln_k<0><<<dim3(BL/32), blk, 0, stream>>>(
            ctxb, woT + (size_t)i*256*256, bo + i*DM, h, hb,
            g1 + i*DM, be1 + i*DM, DM,
            nullptr, nullptr, nullptr, nullptr, nullptr);

        gemm_mfma<1,2><<<dim3(BL/128, 8), blk, 0, stream>>>(
            hb, wf1T + (size_t)i*1024*256, bf1 + i*DFF, (void*)ffbb, nullptr, BL, DFF, DM);

        // fused FF2 + residual + LN2 (+ MLP head on the last layer)
        if (i == 1) {
            gemmln_k<1><<<dim3(BL/32), blk, 0, stream>>>(
                ffbb, wf2T + (size_t)i*256*1024, bf2 + i*DM, h, hb,
                g2 + i*DM, be2 + i*DM, DFF,
                wfc1, bfc1, wfc2, bfc2, out);
        } else {
            gemmln_k<0><<<dim3(BL/32), blk, 0, stream>>>(
                ffbb, wf2T + (size_t)i*256*1024, bf2 + i*DM, h, hb,
                g2 + i*DM, be2 + i*DM, DFF,
                nullptr, nullptr, nullptr, nullptr, nullptr);
        }
    }
}